// Round 12
// baseline (182.840 us; speedup 1.0000x reference)
//
#include <hip/hip_runtime.h>

#pragma clang fp contract(off)

#define N_ANCH 321408
#define NQUAD (N_ANCH / 4)
#define KSEL 4096
#define POST 300
#define H1BINS 1024
#define H1BASE 0x3D40u   // remap: bin = (k>>16) - H1BASE + 1 ; bin 0 = invalid (k==0)
#define CANDCAP 16384

typedef unsigned int u32;
typedef unsigned long long u64;

__device__ __forceinline__ u32 key_of(float m) {
    float s = 1.0f / (1.0f + expf(-m));
    return (s >= 0.05f) ? __float_as_uint(s) : 0u;
}

// ---------------- scoring (vectorized 4 anchors/thread) + coarse histogram ----------------
__global__ __launch_bounds__(1024) void k_keys(const float4* __restrict__ cls4,
                                               uint4* __restrict__ keys4,
                                               u32* __restrict__ hist) {
    __shared__ u32 h0[H1BINS], h1[H1BINS];
    int t = threadIdx.x;
    h0[t] = 0; h1[t] = 0;
    __syncthreads();
    int q = blockIdx.x * 1024 + t;
    if (q < NQUAD) {
        float4 a = cls4[q * 3], b = cls4[q * 3 + 1], d = cls4[q * 3 + 2];
        u32 k0 = key_of(fmaxf(a.x, fmaxf(a.y, a.z)));
        u32 k1 = key_of(fmaxf(a.w, fmaxf(b.x, b.y)));
        u32 k2 = key_of(fmaxf(b.z, fmaxf(b.w, d.x)));
        u32 k3 = key_of(fmaxf(d.y, fmaxf(d.z, d.w)));
        keys4[q] = make_uint4(k0, k1, k2, k3);
        u32* hp = (t & 1) ? h1 : h0;
        atomicAdd(&hp[k0 ? ((k0 >> 16) - H1BASE + 1u) : 0u], 1u);
        atomicAdd(&hp[k1 ? ((k1 >> 16) - H1BASE + 1u) : 0u], 1u);
        atomicAdd(&hp[k2 ? ((k2 >> 16) - H1BASE + 1u) : 0u], 1u);
        atomicAdd(&hp[k3 ? ((k3 >> 16) - H1BASE + 1u) : 0u], 1u);
    }
    __syncthreads();
    u32 c = h0[t] + h1[t];
    if (c) atomicAdd(&hist[t], c);
}

// scan 1024 coarse bins from the top: crossing bin + total valid count
__global__ __launch_bounds__(1024) void k_scan1(const u32* __restrict__ hist, u32* scal) {
    __shared__ u32 sh[1024];
    int t = threadIdx.x;
    int b = 1023 - t;                 // descending bins
    u32 s = hist[b];
    sh[t] = s;
    __syncthreads();
    for (int off = 1; off < 1024; off <<= 1) {
        u32 x = sh[t];
        u32 y = (t >= off) ? sh[t - off] : 0u;
        __syncthreads();
        sh[t] = x + y;
        __syncthreads();
    }
    u32 incl = sh[t];
    u32 excl = incl - s;
    if (excl < 4096u && incl >= 4096u) {
        scal[8] = (b > 0) ? (u32)(b - 1) + H1BASE : 0u;   // actual upper-16 of crossing bin
    }
    if (t == 1023) scal[9] = incl - s;                    // total valid (minus bin 0)
}

// all candidates in bins >= crossing bin; wave-aggregated atomic, vectorized reads
__global__ __launch_bounds__(256) void k_compact(const uint4* __restrict__ keys4,
                                                 u32* scal, u64* __restrict__ cand) {
    int q = blockIdx.x * 256 + threadIdx.x;
    bool act = q < NQUAD;
    uint4 kv = act ? keys4[q] : make_uint4(0, 0, 0, 0);
    u32 thr16 = scal[8];
    int lane = threadIdx.x & 63;
    u32 i0 = (u32)q * 4u;
    bool p0 = kv.x && (kv.x >> 16) >= thr16;
    bool p1 = kv.y && (kv.y >> 16) >= thr16;
    bool p2 = kv.z && (kv.z >> 16) >= thr16;
    bool p3 = kv.w && (kv.w >> 16) >= thr16;
    u64 b0 = __ballot(p0), b1 = __ballot(p1), b2 = __ballot(p2), b3 = __ballot(p3);
    u32 n0 = (u32)__popcll(b0), n1 = (u32)__popcll(b1), n2 = (u32)__popcll(b2);
    u32 nw = n0 + n1 + n2 + (u32)__popcll(b3);
    u32 base = 0;
    if (lane == 0 && nw) base = atomicAdd(&scal[5], nw);
    base = (u32)__shfl((int)base, 0);
    u64 lt = (lane == 0) ? 0ull : (~0ull >> (64 - lane));
    if (p0) { u32 p = base + (u32)__popcll(b0 & lt);
              if (p < CANDCAP) cand[p] = (((u64)kv.x) << 32) | (u32)(~(i0 + 0)); }
    if (p1) { u32 p = base + n0 + (u32)__popcll(b1 & lt);
              if (p < CANDCAP) cand[p] = (((u64)kv.y) << 32) | (u32)(~(i0 + 1)); }
    if (p2) { u32 p = base + n0 + n1 + (u32)__popcll(b2 & lt);
              if (p < CANDCAP) cand[p] = (((u64)kv.z) << 32) | (u32)(~(i0 + 2)); }
    if (p3) { u32 p = base + n0 + n1 + n2 + (u32)__popcll(b3 & lt);
              if (p < CANDCAP) cand[p] = (((u64)kv.w) << 32) | (u32)(~(i0 + 3)); }
}

// 2D partial rank-by-counting
__global__ __launch_bounds__(256) void k_rankpart(const u32* __restrict__ scal,
                                                  const u64* __restrict__ cand,
                                                  u32* __restrict__ rank) {
    __shared__ u64 ch[512];
    u32 nc = scal[5]; if (nc > CANDCAP) nc = CANDCAP;
    u32 cb = blockIdx.x * 256u;
    u32 jb = blockIdx.y * 512u;
    if (cb >= nc || jb >= nc) return;
    u32 t = threadIdx.x;
    for (u32 j = t; j < 512u; j += 256u)
        ch[j] = (jb + j < nc) ? cand[jb + j] : 0ull;
    __syncthreads();
    u32 me = cb + t;
    u64 mine = (me < nc) ? cand[me] : ~0ull;
    u32 r = 0;
    #pragma unroll 8
    for (int j = 0; j < 512; ++j) r += (ch[j] > mine) ? 1u : 0u;
    if (me < nc && r) atomicAdd(&rank[me], r);
}

__global__ void k_scatter(const u32* __restrict__ scal, const u64* __restrict__ cand,
                          const u32* __restrict__ rank, u64* __restrict__ sorted) {
    u32 nc = scal[5]; if (nc > CANDCAP) nc = CANDCAP;
    u32 t = blockIdx.x * 256u + threadIdx.x;
    if (t < nc) {
        u32 r = rank[t];
        if (r < (u32)KSEL) sorted[r] = cand[t];
    }
}

// ---------------- decode helpers ----------
__device__ __forceinline__ void decode_box(u64 cpack, const float* __restrict__ boxp,
                                           const float* __restrict__ anch, float b[7]) {
    u32 key = (u32)(cpack >> 32);
    u32 idx = ~((u32)(cpack & 0xFFFFFFFFull));
    if (key == 0u) idx = 0u;
    const float* a7 = anch + (size_t)idx * 7;
    const float* t7 = boxp + (size_t)idx * 7;
    float xa = a7[0], ya = a7[1], za = a7[2], wa = a7[3], la = a7[4], ha = a7[5], ra = a7[6];
    float xt = t7[0], yt = t7[1], zt = t7[2], wt = t7[3], lt_ = t7[4], ht = t7[5], rt = t7[6];
    za = za + ha * 0.5f;
    float diag = sqrtf(la * la + wa * wa);
    float xg = xt * diag + xa;
    float yg = yt * diag + ya;
    float zg = zt * ha + za;
    float lg = expf(lt_) * la;
    float wg = expf(wt) * wa;
    float hg = expf(ht) * ha;
    float rg = rt + ra;
    zg = zg - hg * 0.5f;
    b[0] = xg; b[1] = yg; b[2] = zg; b[3] = wg; b[4] = lg; b[5] = hg; b[6] = rg;
}

__device__ __forceinline__ float4 standup_box(const float b[7], float* areao) {
    float xg = b[0], yg = b[1], wg = b[3], lg = b[4], rg = b[6];
    float cc = cosf(rg), ss = sinf(rg);
    float dx = wg * 0.5f, dy = lg * 0.5f;
    const float sxs[4] = {-1.f, -1.f, 1.f, 1.f};
    const float sys[4] = {-1.f, 1.f, 1.f, -1.f};
    float minx = 1e30f, miny = 1e30f, maxx = -1e30f, maxy = -1e30f;
    #pragma unroll
    for (int k = 0; k < 4; ++k) {
        float cx = dx * sxs[k], cy = dy * sys[k];
        float px = cx * cc + cy * ss;
        float py = cx * (-ss) + cy * cc;
        px = px + xg; py = py + yg;
        minx = fminf(minx, px); maxx = fmaxf(maxx, px);
        miny = fminf(miny, py); maxy = fmaxf(maxy, py);
    }
    *areao = (maxx - minx) * (maxy - miny);
    return make_float4(minx, miny, maxx, maxy);
}

// decode + standup once per selected box
__global__ void k_decode(const u64* __restrict__ sel2, const float* __restrict__ boxp,
                         const float* __restrict__ anch, float4* __restrict__ bb,
                         float* __restrict__ area) {
    int r = blockIdx.x * blockDim.x + threadIdx.x;
    if (r >= KSEL) return;
    float b[7];
    decode_box(sel2[r], boxp, anch, b);
    float a;
    bb[r] = standup_box(b, &a);
    area[r] = a;
}

// 64x64 IoU mask tile; lower-triangle tiles (cb<rb) are never consumed -> zeros
__global__ __launch_bounds__(64) void k_mask(const float4* __restrict__ bb,
                                             const float* __restrict__ area,
                                             u64* __restrict__ mask) {
    int t = threadIdx.x;
    int rb = blockIdx.y, cb = blockIdx.x;
    int i = rb * 64 + t;
    if (cb < rb) { mask[(size_t)i * 64 + cb] = 0ull; return; }
    __shared__ float4 ob[64];
    __shared__ float oa[64];
    int jg0 = cb * 64;
    ob[t] = bb[jg0 + t];
    oa[t] = area[jg0 + t];
    __syncthreads();
    float4 m4 = bb[i];
    float ma = area[i];
    u64 bits = 0;
    for (int j = 0; j < 64; ++j) {
        int jg = jg0 + j;
        if (jg == i) continue;
        float4 o = ob[j];
        float ltx = fmaxf(m4.x, o.x), lty = fmaxf(m4.y, o.y);
        float rbx = fminf(m4.z, o.z), rby = fminf(m4.w, o.w);
        float w = fmaxf(rbx - ltx, 0.0f), h = fmaxf(rby - lty, 0.0f);
        float inter = w * h;
        float iou = inter / (ma + oa[j] - inter + 1e-8f);
        if (iou > 0.5f) bits |= (1ULL << j);
    }
    mask[(size_t)i * 64 + cb] = bits;
}

// 16-wave windowed greedy NMS. Availability bitmap in LDS. Per round:
//  (A) wave 0 selects the 64 lowest available ranks (prefix-sum + bit walk);
//      threads 64..191 zero the per-round accumulators concurrently
//  (B) 16 waves stage the 64 candidate rows into LDS (wave w: rows 4w..4w+3,
//      each lane one 32B chunk) -- latencies overlap ACROSS waves (TLP)
//  (C) window matrix: thread t -> slot j=t>>4, 4 i-values; LDS atomicOr
//  (D) replicated ordered commit (uniform); apply parallelized over (word, j)
__global__ __launch_bounds__(1024, 1) void k_serial(const u64* __restrict__ mask,
                                                    u32* __restrict__ keep_list,
                                                    u32* __restrict__ scal) {
    int t = threadIdx.x;
    int lane = t & 63;
    __shared__ u64 ls_avail[64];
    __shared__ int ls_cand[64];
    __shared__ u32 ls_m_lo[64], ls_m_hi[64];
    __shared__ u32 ls_acc_lo[64], ls_acc_hi[64];
    __shared__ u64 ls_rows[64 * 66];   // stride 66 u64 (528 B, 16B-aligned, bank-spread)

    if (t < 64) {
        u32 nvt = scal[9];
        u32 nv = (nvt < (u32)KSEL) ? nvt : (u32)KSEL;
        int lo = t * 64;
        u64 a;
        if ((int)nv >= lo + 64) a = ~0ull;
        else if ((int)nv <= lo) a = 0ull;
        else a = (((u64)1) << (nv - lo)) - 1ull;
        ls_avail[t] = a;
    }
    __syncthreads();

    int cnt = 0;
    for (;;) {
        // --- (A) selection on wave 0; zeroing on threads 64..191 ---
        if (t < 64) {
            u64 avail = ls_avail[t];
            u32 pc = (u32)__popcll(avail);
            u32 pre = pc;
            #pragma unroll
            for (int off = 1; off < 64; off <<= 1) {
                u32 y = __shfl_up(pre, (unsigned)off);
                if (lane >= off) pre += y;
            }
            u32 excl = pre - pc;
            ls_cand[t] = -1;
            if (pc && excl < 64u) {
                u64 a = avail;
                u32 o = excl;
                while (a && o < 64u) {
                    int b = (int)__builtin_ctzll(a);
                    a &= a - 1;
                    ls_cand[o++] = t * 64 + b;
                }
            }
        } else if (t < 128) {
            ls_m_lo[t - 64] = 0; ls_m_hi[t - 64] = 0;
        } else if (t < 192) {
            ls_acc_lo[t - 128] = 0; ls_acc_hi[t - 128] = 0;
        }
        __syncthreads();
        int c0 = ls_cand[0];
        if (c0 < 0) break;
        // --- (B) staging: wave w -> rows 4w+ (lane>>4); lane chunk = 32 B ---
        {
            int w = t >> 6;
            int r = w * 4 + (lane >> 4);
            int chunk = lane & 15;
            int cj = ls_cand[r];
            int cs = (cj >= 0) ? cj : c0;
            const uint4* gp = (const uint4*)(mask + (size_t)cs * 64);
            uint4 v0 = gp[chunk * 2];
            uint4 v1 = gp[chunk * 2 + 1];
            if (cj < 0) { v0 = make_uint4(0, 0, 0, 0); v1 = v0; }
            uint4* lp = (uint4*)(ls_rows + (size_t)r * 66);
            lp[chunk * 2] = v0;
            lp[chunk * 2 + 1] = v1;
        }
        __syncthreads();
        // --- (C) window matrix: "i suppresses j" for i<j ---
        {
            int j = t >> 4;
            int i0 = t & 15;
            int cj = ls_cand[j];
            if (cj >= 0) {
                int word = cj >> 6;
                int sh = cj & 63;
                u32 lob = 0, hib = 0;
                #pragma unroll
                for (int k = 0; k < 4; ++k) {
                    int i = i0 + 16 * k;
                    if (i < j) {
                        u64 v = ls_rows[(size_t)i * 66 + word];
                        u32 bit = (u32)((v >> sh) & 1ull);
                        if (k < 2) lob |= bit << i;
                        else hib |= bit << (i - 32);
                    }
                }
                if (lob) atomicOr(&ls_m_lo[j], lob);
                if (hib) atomicOr(&ls_m_hi[j], hib);
            }
        }
        __syncthreads();
        // --- (D) ordered commit, replicated on all threads (uniform) ---
        u64 committed = 0;
        bool stop = false;
        for (int j = 0; j < 64; ++j) {
            int cj = ls_cand[j];
            if (cj < 0) continue;
            u64 mj = (u64)ls_m_lo[j] | ((u64)ls_m_hi[j] << 32);
            if (mj & committed) continue;
            if (t == 0 && cnt < POST) keep_list[cnt] = (u32)cj;
            committed |= (1ull << j);
            cnt++;
            if (cnt >= POST) { stop = true; break; }
        }
        if (stop) break;
        // --- apply: thread t -> word (t&63), j in [(t>>6)*4, +4) ---
        {
            int word = t & 63;
            int j0 = (t >> 6) * 4;
            u64 acc = 0;
            #pragma unroll
            for (int k = 0; k < 4; ++k) {
                int j = j0 + k;
                if ((committed >> j) & 1ull) acc |= ls_rows[(size_t)j * 66 + word];
            }
            u32 alo = (u32)acc, ahi = (u32)(acc >> 32);
            if (alo) atomicOr(&ls_acc_lo[word], alo);
            if (ahi) atomicOr(&ls_acc_hi[word], ahi);
        }
        __syncthreads();
        if (t < 64) {
            u64 a = ls_avail[t];
            a &= ~((u64)ls_acc_lo[t] | ((u64)ls_acc_hi[t] << 32));
            for (int j = 0; j < 64; ++j) {
                if ((committed >> j) & 1ull) {
                    int cj = ls_cand[j];
                    if ((cj >> 6) == t) a &= ~(((u64)1) << (cj & 63));
                }
            }
            ls_avail[t] = a;
        }
        __syncthreads();
    }
    if (t == 0) scal[7] = (u32)(cnt < POST ? cnt : POST);
}

__global__ void k_final(const u32* __restrict__ scal, const u32* __restrict__ keep_list,
                        const u64* __restrict__ sel2, const float* __restrict__ boxp,
                        const float* __restrict__ anch, const float* __restrict__ cls,
                        const float* __restrict__ dirp, float* __restrict__ out) {
    int t = blockIdx.x * blockDim.x + threadIdx.x;
    if (t >= POST) return;
    u32 m = scal[7];
    float* ob = out;
    float* os = out + POST * 7;
    float* ol = os + POST;
    float* ov = ol + POST;
    if (t < (int)m) {
        u32 r = keep_list[t];
        u64 cp = sel2[r];
        u32 key = (u32)(cp >> 32);
        u32 i = ~((u32)(cp & 0xFFFFFFFFull));
        float b[7];
        decode_box(cp, boxp, anch, b);
        float d0 = dirp[(size_t)i * 2], d1 = dirp[(size_t)i * 2 + 1];
        int dl = (d1 > d0) ? 1 : 0;
        int pos = (b[6] > 0.0f) ? 1 : 0;
        if (pos ^ dl) b[6] = b[6] + 3.14159265358979323846f;
        for (int q = 0; q < 7; ++q) ob[(size_t)t * 7 + q] = b[q];
        os[t] = __uint_as_float(key);
        float s0 = 1.0f / (1.0f + expf(-cls[(size_t)i * 3]));
        float s1 = 1.0f / (1.0f + expf(-cls[(size_t)i * 3 + 1]));
        float s2 = 1.0f / (1.0f + expf(-cls[(size_t)i * 3 + 2]));
        int lab = 0; float best = s0;
        if (s1 > best) { lab = 1; best = s1; }
        if (s2 > best) { lab = 2; }
        ol[t] = (float)lab;
        ov[t] = 1.0f;
    } else {
        for (int q = 0; q < 7; ++q) ob[(size_t)t * 7 + q] = 0.0f;
        os[t] = 0.0f;
        ol[t] = -1.0f;
        ov[t] = 0.0f;
    }
}

extern "C" void kernel_launch(void* const* d_in, const int* in_sizes, int n_in,
                              void* d_out, int out_size, void* d_ws, size_t ws_size,
                              hipStream_t stream) {
    const float* box_preds = (const float*)d_in[0];
    const float* cls_preds = (const float*)d_in[1];
    const float* dir_preds = (const float*)d_in[2];
    const float* anchors   = (const float*)d_in[3];
    float* out = (float*)d_out;

    unsigned char* w = (unsigned char*)d_ws;
    size_t off = 0;
    auto nxt = [&](size_t bytes) -> void* {
        void* p = (void*)(w + off);
        off = (off + bytes + 255) & ~(size_t)255;
        return p;
    };
    // memset region (contiguous): hist1 | scal | sel2 | rank
    u32* hist1     = (u32*)nxt(H1BINS * 4);            //  4096 B
    u32* scal      = (u32*)nxt(64 * 4);                //   256 B
    u64* sel2      = (u64*)nxt((size_t)KSEL * 8);      // 32768 B
    u32* rank      = (u32*)nxt((size_t)CANDCAP * 4);   // 65536 B
    u64* cand      = (u64*)nxt((size_t)CANDCAP * 8);
    u64* mask      = (u64*)nxt((size_t)KSEL * 64 * 8);
    u32* keep_list = (u32*)nxt(512 * 4);
    float4* bb     = (float4*)nxt((size_t)KSEL * 16);
    float* area    = (float*)nxt((size_t)KSEL * 4);
    u32* keys      = (u32*)nxt((size_t)N_ANCH * 4);

    hipMemsetAsync(hist1, 0,
                   (size_t)H1BINS * 4 + 256 + (size_t)KSEL * 8 + (size_t)CANDCAP * 4,
                   stream);

    k_keys<<<(NQUAD + 1023) / 1024, 1024, 0, stream>>>((const float4*)cls_preds,
                                                       (uint4*)keys, hist1);
    k_scan1<<<1, 1024, 0, stream>>>(hist1, scal);
    k_compact<<<(NQUAD + 255) / 256, 256, 0, stream>>>((const uint4*)keys, scal, cand);
    dim3 rg(CANDCAP / 256, CANDCAP / 512);
    k_rankpart<<<rg, 256, 0, stream>>>(scal, cand, rank);
    k_scatter<<<CANDCAP / 256, 256, 0, stream>>>(scal, cand, rank, sel2);
    k_decode<<<KSEL / 256, 256, 0, stream>>>(sel2, box_preds, anchors, bb, area);
    dim3 mg(64, 64);
    k_mask<<<mg, 64, 0, stream>>>(bb, area, mask);
    k_serial<<<1, 1024, 0, stream>>>(mask, keep_list, scal);
    k_final<<<2, 256, 0, stream>>>(scal, keep_list, sel2, box_preds, anchors, cls_preds, dir_preds, out);
}

// Round 13
// 136.713 us; speedup vs baseline: 1.3374x; 1.3374x over previous
//
#include <hip/hip_runtime.h>

#pragma clang fp contract(off)

#define N_ANCH 321408
#define NQUAD (N_ANCH / 4)
#define KSEL 4096
#define POST 300
#define H1BINS 1024
#define H1BASE 0x3D40u   // remap: bin = (k>>16) - H1BASE + 1 ; bin 0 = invalid (k==0)
#define CANDCAP 16384
#define SUPCAP 16        // max stored suppression targets per row; overflow -> dense fallback

typedef unsigned int u32;
typedef unsigned long long u64;

__device__ __forceinline__ u32 key_of(float m) {
    float s = 1.0f / (1.0f + expf(-m));
    return (s >= 0.05f) ? __float_as_uint(s) : 0u;
}

// ---------------- scoring (vectorized 4 anchors/thread) + coarse histogram ----------------
__global__ __launch_bounds__(1024) void k_keys(const float4* __restrict__ cls4,
                                               uint4* __restrict__ keys4,
                                               u32* __restrict__ hist) {
    __shared__ u32 h0[H1BINS], h1[H1BINS];
    int t = threadIdx.x;
    h0[t] = 0; h1[t] = 0;
    __syncthreads();
    int q = blockIdx.x * 1024 + t;
    if (q < NQUAD) {
        float4 a = cls4[q * 3], b = cls4[q * 3 + 1], d = cls4[q * 3 + 2];
        u32 k0 = key_of(fmaxf(a.x, fmaxf(a.y, a.z)));
        u32 k1 = key_of(fmaxf(a.w, fmaxf(b.x, b.y)));
        u32 k2 = key_of(fmaxf(b.z, fmaxf(b.w, d.x)));
        u32 k3 = key_of(fmaxf(d.y, fmaxf(d.z, d.w)));
        keys4[q] = make_uint4(k0, k1, k2, k3);
        u32* hp = (t & 1) ? h1 : h0;
        atomicAdd(&hp[k0 ? ((k0 >> 16) - H1BASE + 1u) : 0u], 1u);
        atomicAdd(&hp[k1 ? ((k1 >> 16) - H1BASE + 1u) : 0u], 1u);
        atomicAdd(&hp[k2 ? ((k2 >> 16) - H1BASE + 1u) : 0u], 1u);
        atomicAdd(&hp[k3 ? ((k3 >> 16) - H1BASE + 1u) : 0u], 1u);
    }
    __syncthreads();
    u32 c = h0[t] + h1[t];
    if (c) atomicAdd(&hist[t], c);
}

// scan 1024 coarse bins from the top: crossing bin + total valid count
__global__ __launch_bounds__(1024) void k_scan1(const u32* __restrict__ hist, u32* scal) {
    __shared__ u32 sh[1024];
    int t = threadIdx.x;
    int b = 1023 - t;                 // descending bins
    u32 s = hist[b];
    sh[t] = s;
    __syncthreads();
    for (int off = 1; off < 1024; off <<= 1) {
        u32 x = sh[t];
        u32 y = (t >= off) ? sh[t - off] : 0u;
        __syncthreads();
        sh[t] = x + y;
        __syncthreads();
    }
    u32 incl = sh[t];
    u32 excl = incl - s;
    if (excl < 4096u && incl >= 4096u) {
        scal[8] = (b > 0) ? (u32)(b - 1) + H1BASE : 0u;   // actual upper-16 of crossing bin
    }
    if (t == 1023) scal[9] = incl - s;                    // total valid (minus bin 0)
}

// all candidates in bins >= crossing bin; wave-aggregated atomic, vectorized reads
__global__ __launch_bounds__(256) void k_compact(const uint4* __restrict__ keys4,
                                                 u32* scal, u64* __restrict__ cand) {
    int q = blockIdx.x * 256 + threadIdx.x;
    bool act = q < NQUAD;
    uint4 kv = act ? keys4[q] : make_uint4(0, 0, 0, 0);
    u32 thr16 = scal[8];
    int lane = threadIdx.x & 63;
    u32 i0 = (u32)q * 4u;
    bool p0 = kv.x && (kv.x >> 16) >= thr16;
    bool p1 = kv.y && (kv.y >> 16) >= thr16;
    bool p2 = kv.z && (kv.z >> 16) >= thr16;
    bool p3 = kv.w && (kv.w >> 16) >= thr16;
    u64 b0 = __ballot(p0), b1 = __ballot(p1), b2 = __ballot(p2), b3 = __ballot(p3);
    u32 n0 = (u32)__popcll(b0), n1 = (u32)__popcll(b1), n2 = (u32)__popcll(b2);
    u32 nw = n0 + n1 + n2 + (u32)__popcll(b3);
    u32 base = 0;
    if (lane == 0 && nw) base = atomicAdd(&scal[5], nw);
    base = (u32)__shfl((int)base, 0);
    u64 lt = (lane == 0) ? 0ull : (~0ull >> (64 - lane));
    if (p0) { u32 p = base + (u32)__popcll(b0 & lt);
              if (p < CANDCAP) cand[p] = (((u64)kv.x) << 32) | (u32)(~(i0 + 0)); }
    if (p1) { u32 p = base + n0 + (u32)__popcll(b1 & lt);
              if (p < CANDCAP) cand[p] = (((u64)kv.y) << 32) | (u32)(~(i0 + 1)); }
    if (p2) { u32 p = base + n0 + n1 + (u32)__popcll(b2 & lt);
              if (p < CANDCAP) cand[p] = (((u64)kv.z) << 32) | (u32)(~(i0 + 2)); }
    if (p3) { u32 p = base + n0 + n1 + n2 + (u32)__popcll(b3 & lt);
              if (p < CANDCAP) cand[p] = (((u64)kv.w) << 32) | (u32)(~(i0 + 3)); }
}

// 2D partial rank-by-counting
__global__ __launch_bounds__(256) void k_rankpart(const u32* __restrict__ scal,
                                                  const u64* __restrict__ cand,
                                                  u32* __restrict__ rank) {
    __shared__ u64 ch[512];
    u32 nc = scal[5]; if (nc > CANDCAP) nc = CANDCAP;
    u32 cb = blockIdx.x * 256u;
    u32 jb = blockIdx.y * 512u;
    if (cb >= nc || jb >= nc) return;
    u32 t = threadIdx.x;
    for (u32 j = t; j < 512u; j += 256u)
        ch[j] = (jb + j < nc) ? cand[jb + j] : 0ull;
    __syncthreads();
    u32 me = cb + t;
    u64 mine = (me < nc) ? cand[me] : ~0ull;
    u32 r = 0;
    #pragma unroll 8
    for (int j = 0; j < 512; ++j) r += (ch[j] > mine) ? 1u : 0u;
    if (me < nc && r) atomicAdd(&rank[me], r);
}

__global__ void k_scatter(const u32* __restrict__ scal, const u64* __restrict__ cand,
                          const u32* __restrict__ rank, u64* __restrict__ sorted) {
    u32 nc = scal[5]; if (nc > CANDCAP) nc = CANDCAP;
    u32 t = blockIdx.x * 256u + threadIdx.x;
    if (t < nc) {
        u32 r = rank[t];
        if (r < (u32)KSEL) sorted[r] = cand[t];
    }
}

// ---------------- decode helpers ----------
__device__ __forceinline__ void decode_box(u64 cpack, const float* __restrict__ boxp,
                                           const float* __restrict__ anch, float b[7]) {
    u32 key = (u32)(cpack >> 32);
    u32 idx = ~((u32)(cpack & 0xFFFFFFFFull));
    if (key == 0u) idx = 0u;
    const float* a7 = anch + (size_t)idx * 7;
    const float* t7 = boxp + (size_t)idx * 7;
    float xa = a7[0], ya = a7[1], za = a7[2], wa = a7[3], la = a7[4], ha = a7[5], ra = a7[6];
    float xt = t7[0], yt = t7[1], zt = t7[2], wt = t7[3], lt_ = t7[4], ht = t7[5], rt = t7[6];
    za = za + ha * 0.5f;
    float diag = sqrtf(la * la + wa * wa);
    float xg = xt * diag + xa;
    float yg = yt * diag + ya;
    float zg = zt * ha + za;
    float lg = expf(lt_) * la;
    float wg = expf(wt) * wa;
    float hg = expf(ht) * ha;
    float rg = rt + ra;
    zg = zg - hg * 0.5f;
    b[0] = xg; b[1] = yg; b[2] = zg; b[3] = wg; b[4] = lg; b[5] = hg; b[6] = rg;
}

__device__ __forceinline__ float4 standup_box(const float b[7], float* areao) {
    float xg = b[0], yg = b[1], wg = b[3], lg = b[4], rg = b[6];
    float cc = cosf(rg), ss = sinf(rg);
    float dx = wg * 0.5f, dy = lg * 0.5f;
    const float sxs[4] = {-1.f, -1.f, 1.f, 1.f};
    const float sys[4] = {-1.f, 1.f, 1.f, -1.f};
    float minx = 1e30f, miny = 1e30f, maxx = -1e30f, maxy = -1e30f;
    #pragma unroll
    for (int k = 0; k < 4; ++k) {
        float cx = dx * sxs[k], cy = dy * sys[k];
        float px = cx * cc + cy * ss;
        float py = cx * (-ss) + cy * cc;
        px = px + xg; py = py + yg;
        minx = fminf(minx, px); maxx = fmaxf(maxx, px);
        miny = fminf(miny, py); maxy = fmaxf(maxy, py);
    }
    *areao = (maxx - minx) * (maxy - miny);
    return make_float4(minx, miny, maxx, maxy);
}

// decode + standup once per selected box
__global__ void k_decode(const u64* __restrict__ sel2, const float* __restrict__ boxp,
                         const float* __restrict__ anch, float4* __restrict__ bb,
                         float* __restrict__ area) {
    int r = blockIdx.x * blockDim.x + threadIdx.x;
    if (r >= KSEL) return;
    float b[7];
    decode_box(sel2[r], boxp, anch, b);
    float a;
    bb[r] = standup_box(b, &a);
    area[r] = a;
}

// 64x64 IoU mask tile + sparse suppression lists (rank i -> ranks j>i, IoU>0.5).
// Lower-triangle tiles (cb<rb) zero; each unordered pair recorded once in the
// lower-rank row's list. Dense mask kept for overflow fallback (cnt > SUPCAP).
__global__ __launch_bounds__(64) void k_mask(const float4* __restrict__ bb,
                                             const float* __restrict__ area,
                                             u64* __restrict__ mask,
                                             u32* __restrict__ sup_cnt,
                                             u32* __restrict__ sup_ent) {
    int t = threadIdx.x;
    int rb = blockIdx.y, cb = blockIdx.x;
    int i = rb * 64 + t;
    if (cb < rb) { mask[(size_t)i * 64 + cb] = 0ull; return; }
    __shared__ float4 ob[64];
    __shared__ float oa[64];
    int jg0 = cb * 64;
    ob[t] = bb[jg0 + t];
    oa[t] = area[jg0 + t];
    __syncthreads();
    float4 m4 = bb[i];
    float ma = area[i];
    u64 bits = 0;
    for (int j = 0; j < 64; ++j) {
        int jg = jg0 + j;
        if (jg == i) continue;
        float4 o = ob[j];
        float ltx = fmaxf(m4.x, o.x), lty = fmaxf(m4.y, o.y);
        float rbx = fminf(m4.z, o.z), rby = fminf(m4.w, o.w);
        float w = fmaxf(rbx - ltx, 0.0f), h = fmaxf(rby - lty, 0.0f);
        float inter = w * h;
        float iou = inter / (ma + oa[j] - inter + 1e-8f);
        if (iou > 0.5f) bits |= (1ULL << j);
    }
    mask[(size_t)i * 64 + cb] = bits;
    // sparse list entries: only targets with higher rank
    u64 bset = bits;
    while (bset) {
        int j = (int)__builtin_ctzll(bset);
        bset &= bset - 1;
        int jg = jg0 + j;
        if (jg > i) {
            u32 p = atomicAdd(&sup_cnt[i], 1u);
            if (p < SUPCAP) sup_ent[(size_t)i * SUPCAP + p] = (u32)jg;
        }
    }
}

__device__ __forceinline__ u64 shflx_u64(u64 v, int m) {
    int lo = __shfl_xor((int)(u32)(v & 0xFFFFFFFFull), m);
    int hi = __shfl_xor((int)(u32)(v >> 32), m);
    return (((u64)(u32)hi) << 32) | (u32)lo;
}

// one wave. Window-64 greedy over SPARSE suppression lists.
// Per round: select 64 lowest available ranks; lane j fetches its candidate's
// <=SUPCAP list entries (one parallel scattered-load latency); converts ranks ->
// window slots via LDS avail/excl; commit via 64 ballots; apply via LDS atomicAnd.
// Overflow rows (cnt > SUPCAP) fall back to cooperative dense-row reads (never
// triggered for random data; exact for any data).
__global__ __launch_bounds__(64, 1) void k_serial(const u64* __restrict__ mask,
                                                  const u32* __restrict__ sup_cnt,
                                                  const u32* __restrict__ sup_ent,
                                                  u32* __restrict__ keep_list,
                                                  u32* __restrict__ scal) {
    int lane = threadIdx.x;
    __shared__ u64 ls_avail[64];
    __shared__ u32 ls_excl[64];
    __shared__ int ls_cand[64];
    {
        u32 nvt = scal[9];
        u32 nv = (nvt < (u32)KSEL) ? nvt : (u32)KSEL;
        int lo = lane * 64;
        u64 a;
        if ((int)nv >= lo + 64) a = ~0ull;
        else if ((int)nv <= lo) a = 0ull;
        else a = (((u64)1) << (nv - lo)) - 1ull;
        ls_avail[lane] = a;
    }
    __syncthreads();

    int cnt = 0;
    for (;;) {
        // --- select first 64 available ranks ---
        u64 avail = ls_avail[lane];
        u32 pc = (u32)__popcll(avail);
        u32 pre = pc;
        #pragma unroll
        for (int off = 1; off < 64; off <<= 1) {
            u32 y = __shfl_up(pre, (unsigned)off);
            if (lane >= off) pre += y;
        }
        u32 excl = pre - pc;
        ls_excl[lane] = excl;
        ls_cand[lane] = -1;
        __syncthreads();
        if (pc && excl < 64u) {
            u64 a = avail;
            u32 o = excl;
            while (a && o < 64u) {
                int b = (int)__builtin_ctzll(a);
                a &= a - 1;
                ls_cand[o++] = lane * 64 + b;
            }
        }
        __syncthreads();
        int cj = ls_cand[lane];
        bool valid = cj >= 0;
        u64 wv = __ballot(valid);
        if (ls_cand[0] < 0) break;
        // --- fetch my candidate's list (parallel scattered loads) ---
        u32 scnt = valid ? sup_cnt[cj] : 0u;
        u32 ecap = (scnt < (u32)SUPCAP) ? scnt : (u32)SUPCAP;
        u32 ent[SUPCAP];
        #pragma unroll
        for (int e = 0; e < SUPCAP; ++e)
            ent[e] = (valid && (u32)e < ecap) ? sup_ent[(size_t)cj * SUPCAP + e] : 0xFFFFFFFFu;
        bool ovf = valid && (scnt > (u32)SUPCAP);
        // --- build my slot-row: which window slots my candidate suppresses ---
        u64 row = 0;
        #pragma unroll
        for (int e = 0; e < SUPCAP; ++e) {
            u32 r = ent[e];
            if (r < (u32)KSEL) {
                u64 aw = ls_avail[r >> 6];
                if ((aw >> (r & 63)) & 1ull) {
                    u64 below = (r & 63) ? (aw & ((1ull << (r & 63)) - 1ull)) : 0ull;
                    u32 slot = ls_excl[r >> 6] + (u32)__popcll(below);
                    if (slot < 64u) row |= 1ull << slot;
                }
            }
        }
        // --- overflow fallback: cooperative dense-row conversion (rare) ---
        u64 ovfm = __ballot(ovf);
        while (ovfm) {
            int src = (int)__builtin_ctzll(ovfm);
            ovfm &= ovfm - 1;
            int ci = __shfl(cj, src);
            u64 w = mask[(size_t)ci * 64 + lane];
            u64 aw = ls_avail[lane];
            u64 ww = w & aw;
            u64 partial = 0;
            while (ww) {
                int b = (int)__builtin_ctzll(ww);
                ww &= ww - 1;
                u64 below = b ? (aw & ((1ull << b) - 1ull)) : 0ull;
                u32 slot = ls_excl[lane] + (u32)__popcll(below);
                if (slot < 64u) partial |= 1ull << slot;
            }
            #pragma unroll
            for (int m = 32; m >= 1; m >>= 1) partial |= shflx_u64(partial, m);
            if (lane == src) row = partial;
        }
        // --- ordered commit via ballots (exact greedy within window) ---
        u64 committed = 0;
        bool stop = false;
        for (int j = 0; j < 64; ++j) {
            if (!((wv >> j) & 1ull)) continue;
            int mybit = (int)((row >> j) & 1ull) & (int)((committed >> lane) & 1ull);
            u64 sup = __ballot(mybit);
            if (sup) continue;
            if (lane == 0 && cnt < POST) keep_list[cnt] = (u32)ls_cand[j];
            committed |= 1ull << j;
            cnt++;
            if (cnt >= POST) { stop = true; break; }
        }
        // --- apply: committed lanes clear their targets + own bit (LDS atomics) ---
        if (!stop) {
            bool amC = ((committed >> lane) & 1ull) != 0;
            if (amC) {
                #pragma unroll
                for (int e = 0; e < SUPCAP; ++e) {
                    u32 r = ent[e];
                    if (r < (u32)KSEL)
                        atomicAnd(&ls_avail[r >> 6], ~(1ull << (r & 63)));
                }
                atomicAnd(&ls_avail[cj >> 6], ~(1ull << (cj & 63)));
            }
            u64 ovfc = __ballot(ovf && amC);
            while (ovfc) {
                int src = (int)__builtin_ctzll(ovfc);
                ovfc &= ovfc - 1;
                int ci = __shfl(cj, src);
                u64 w = mask[(size_t)ci * 64 + lane];
                if (w) atomicAnd(&ls_avail[lane], ~w);
            }
            __syncthreads();
        }
        if (stop) break;
    }
    if (lane == 0) scal[7] = (u32)(cnt < POST ? cnt : POST);
}

__global__ void k_final(const u32* __restrict__ scal, const u32* __restrict__ keep_list,
                        const u64* __restrict__ sel2, const float* __restrict__ boxp,
                        const float* __restrict__ anch, const float* __restrict__ cls,
                        const float* __restrict__ dirp, float* __restrict__ out) {
    int t = blockIdx.x * blockDim.x + threadIdx.x;
    if (t >= POST) return;
    u32 m = scal[7];
    float* ob = out;
    float* os = out + POST * 7;
    float* ol = os + POST;
    float* ov = ol + POST;
    if (t < (int)m) {
        u32 r = keep_list[t];
        u64 cp = sel2[r];
        u32 key = (u32)(cp >> 32);
        u32 i = ~((u32)(cp & 0xFFFFFFFFull));
        float b[7];
        decode_box(cp, boxp, anch, b);
        float d0 = dirp[(size_t)i * 2], d1 = dirp[(size_t)i * 2 + 1];
        int dl = (d1 > d0) ? 1 : 0;
        int pos = (b[6] > 0.0f) ? 1 : 0;
        if (pos ^ dl) b[6] = b[6] + 3.14159265358979323846f;
        for (int q = 0; q < 7; ++q) ob[(size_t)t * 7 + q] = b[q];
        os[t] = __uint_as_float(key);
        float s0 = 1.0f / (1.0f + expf(-cls[(size_t)i * 3]));
        float s1 = 1.0f / (1.0f + expf(-cls[(size_t)i * 3 + 1]));
        float s2 = 1.0f / (1.0f + expf(-cls[(size_t)i * 3 + 2]));
        int lab = 0; float best = s0;
        if (s1 > best) { lab = 1; best = s1; }
        if (s2 > best) { lab = 2; }
        ol[t] = (float)lab;
        ov[t] = 1.0f;
    } else {
        for (int q = 0; q < 7; ++q) ob[(size_t)t * 7 + q] = 0.0f;
        os[t] = 0.0f;
        ol[t] = -1.0f;
        ov[t] = 0.0f;
    }
}

extern "C" void kernel_launch(void* const* d_in, const int* in_sizes, int n_in,
                              void* d_out, int out_size, void* d_ws, size_t ws_size,
                              hipStream_t stream) {
    const float* box_preds = (const float*)d_in[0];
    const float* cls_preds = (const float*)d_in[1];
    const float* dir_preds = (const float*)d_in[2];
    const float* anchors   = (const float*)d_in[3];
    float* out = (float*)d_out;

    unsigned char* w = (unsigned char*)d_ws;
    size_t off = 0;
    auto nxt = [&](size_t bytes) -> void* {
        void* p = (void*)(w + off);
        off = (off + bytes + 255) & ~(size_t)255;
        return p;
    };
    // memset region (contiguous): hist1 | scal | sel2 | rank | sup_cnt
    u32* hist1     = (u32*)nxt(H1BINS * 4);            //  4096 B
    u32* scal      = (u32*)nxt(64 * 4);                //   256 B
    u64* sel2      = (u64*)nxt((size_t)KSEL * 8);      // 32768 B
    u32* rank      = (u32*)nxt((size_t)CANDCAP * 4);   // 65536 B
    u32* sup_cnt   = (u32*)nxt((size_t)KSEL * 4);      // 16384 B
    u64* cand      = (u64*)nxt((size_t)CANDCAP * 8);
    u64* mask      = (u64*)nxt((size_t)KSEL * 64 * 8);
    u32* sup_ent   = (u32*)nxt((size_t)KSEL * SUPCAP * 4);
    u32* keep_list = (u32*)nxt(512 * 4);
    float4* bb     = (float4*)nxt((size_t)KSEL * 16);
    float* area    = (float*)nxt((size_t)KSEL * 4);
    u32* keys      = (u32*)nxt((size_t)N_ANCH * 4);

    hipMemsetAsync(hist1, 0,
                   (size_t)H1BINS * 4 + 256 + (size_t)KSEL * 8 + (size_t)CANDCAP * 4
                   + (size_t)KSEL * 4,
                   stream);

    k_keys<<<(NQUAD + 1023) / 1024, 1024, 0, stream>>>((const float4*)cls_preds,
                                                       (uint4*)keys, hist1);
    k_scan1<<<1, 1024, 0, stream>>>(hist1, scal);
    k_compact<<<(NQUAD + 255) / 256, 256, 0, stream>>>((const uint4*)keys, scal, cand);
    dim3 rg(CANDCAP / 256, CANDCAP / 512);
    k_rankpart<<<rg, 256, 0, stream>>>(scal, cand, rank);
    k_scatter<<<CANDCAP / 256, 256, 0, stream>>>(scal, cand, rank, sel2);
    k_decode<<<KSEL / 256, 256, 0, stream>>>(sel2, box_preds, anchors, bb, area);
    dim3 mg(64, 64);
    k_mask<<<mg, 64, 0, stream>>>(bb, area, mask, sup_cnt, sup_ent);
    k_serial<<<1, 64, 0, stream>>>(mask, sup_cnt, sup_ent, keep_list, scal);
    k_final<<<2, 256, 0, stream>>>(scal, keep_list, sel2, box_preds, anchors, cls_preds, dir_preds, out);
}

// Round 14
// 133.741 us; speedup vs baseline: 1.3671x; 1.0222x over previous
//
#include <hip/hip_runtime.h>

#pragma clang fp contract(off)

#define N_ANCH 321408
#define NQUAD (N_ANCH / 4)
#define KSEL 4096
#define POST 300
#define H1BINS 1024
#define H1BASE 0x3D40u   // remap: bin = (k>>16) - H1BASE + 1 ; bin 0 = invalid (k==0)
#define CANDCAP 16384
#define SUPCAP 16        // max stored suppression targets per row; overflow -> dense fallback
#define WW 256           // NMS window width (4 waves)
#define OVFCAP 32

typedef unsigned int u32;
typedef unsigned long long u64;

__device__ __forceinline__ u32 key_of(float m) {
    float s = 1.0f / (1.0f + expf(-m));
    return (s >= 0.05f) ? __float_as_uint(s) : 0u;
}

// ---------------- scoring (vectorized 4 anchors/thread) + coarse histogram ----------------
__global__ __launch_bounds__(1024) void k_keys(const float4* __restrict__ cls4,
                                               uint4* __restrict__ keys4,
                                               u32* __restrict__ hist) {
    __shared__ u32 h0[H1BINS], h1[H1BINS];
    int t = threadIdx.x;
    h0[t] = 0; h1[t] = 0;
    __syncthreads();
    int q = blockIdx.x * 1024 + t;
    if (q < NQUAD) {
        float4 a = cls4[q * 3], b = cls4[q * 3 + 1], d = cls4[q * 3 + 2];
        u32 k0 = key_of(fmaxf(a.x, fmaxf(a.y, a.z)));
        u32 k1 = key_of(fmaxf(a.w, fmaxf(b.x, b.y)));
        u32 k2 = key_of(fmaxf(b.z, fmaxf(b.w, d.x)));
        u32 k3 = key_of(fmaxf(d.y, fmaxf(d.z, d.w)));
        keys4[q] = make_uint4(k0, k1, k2, k3);
        u32* hp = (t & 1) ? h1 : h0;
        atomicAdd(&hp[k0 ? ((k0 >> 16) - H1BASE + 1u) : 0u], 1u);
        atomicAdd(&hp[k1 ? ((k1 >> 16) - H1BASE + 1u) : 0u], 1u);
        atomicAdd(&hp[k2 ? ((k2 >> 16) - H1BASE + 1u) : 0u], 1u);
        atomicAdd(&hp[k3 ? ((k3 >> 16) - H1BASE + 1u) : 0u], 1u);
    }
    __syncthreads();
    u32 c = h0[t] + h1[t];
    if (c) atomicAdd(&hist[t], c);
}

// scan 1024 coarse bins from the top: crossing bin + total valid count
__global__ __launch_bounds__(1024) void k_scan1(const u32* __restrict__ hist, u32* scal) {
    __shared__ u32 sh[1024];
    int t = threadIdx.x;
    int b = 1023 - t;                 // descending bins
    u32 s = hist[b];
    sh[t] = s;
    __syncthreads();
    for (int off = 1; off < 1024; off <<= 1) {
        u32 x = sh[t];
        u32 y = (t >= off) ? sh[t - off] : 0u;
        __syncthreads();
        sh[t] = x + y;
        __syncthreads();
    }
    u32 incl = sh[t];
    u32 excl = incl - s;
    if (excl < 4096u && incl >= 4096u) {
        scal[8] = (b > 0) ? (u32)(b - 1) + H1BASE : 0u;   // actual upper-16 of crossing bin
    }
    if (t == 1023) scal[9] = incl - s;                    // total valid (minus bin 0)
}

// all candidates in bins >= crossing bin; wave-aggregated atomic, vectorized reads
__global__ __launch_bounds__(256) void k_compact(const uint4* __restrict__ keys4,
                                                 u32* scal, u64* __restrict__ cand) {
    int q = blockIdx.x * 256 + threadIdx.x;
    bool act = q < NQUAD;
    uint4 kv = act ? keys4[q] : make_uint4(0, 0, 0, 0);
    u32 thr16 = scal[8];
    int lane = threadIdx.x & 63;
    u32 i0 = (u32)q * 4u;
    bool p0 = kv.x && (kv.x >> 16) >= thr16;
    bool p1 = kv.y && (kv.y >> 16) >= thr16;
    bool p2 = kv.z && (kv.z >> 16) >= thr16;
    bool p3 = kv.w && (kv.w >> 16) >= thr16;
    u64 b0 = __ballot(p0), b1 = __ballot(p1), b2 = __ballot(p2), b3 = __ballot(p3);
    u32 n0 = (u32)__popcll(b0), n1 = (u32)__popcll(b1), n2 = (u32)__popcll(b2);
    u32 nw = n0 + n1 + n2 + (u32)__popcll(b3);
    u32 base = 0;
    if (lane == 0 && nw) base = atomicAdd(&scal[5], nw);
    base = (u32)__shfl((int)base, 0);
    u64 lt = (lane == 0) ? 0ull : (~0ull >> (64 - lane));
    if (p0) { u32 p = base + (u32)__popcll(b0 & lt);
              if (p < CANDCAP) cand[p] = (((u64)kv.x) << 32) | (u32)(~(i0 + 0)); }
    if (p1) { u32 p = base + n0 + (u32)__popcll(b1 & lt);
              if (p < CANDCAP) cand[p] = (((u64)kv.y) << 32) | (u32)(~(i0 + 1)); }
    if (p2) { u32 p = base + n0 + n1 + (u32)__popcll(b2 & lt);
              if (p < CANDCAP) cand[p] = (((u64)kv.z) << 32) | (u32)(~(i0 + 2)); }
    if (p3) { u32 p = base + n0 + n1 + n2 + (u32)__popcll(b3 & lt);
              if (p < CANDCAP) cand[p] = (((u64)kv.w) << 32) | (u32)(~(i0 + 3)); }
}

// 2D partial rank-by-counting
__global__ __launch_bounds__(256) void k_rankpart(const u32* __restrict__ scal,
                                                  const u64* __restrict__ cand,
                                                  u32* __restrict__ rank) {
    __shared__ u64 ch[512];
    u32 nc = scal[5]; if (nc > CANDCAP) nc = CANDCAP;
    u32 cb = blockIdx.x * 256u;
    u32 jb = blockIdx.y * 512u;
    if (cb >= nc || jb >= nc) return;
    u32 t = threadIdx.x;
    for (u32 j = t; j < 512u; j += 256u)
        ch[j] = (jb + j < nc) ? cand[jb + j] : 0ull;
    __syncthreads();
    u32 me = cb + t;
    u64 mine = (me < nc) ? cand[me] : ~0ull;
    u32 r = 0;
    #pragma unroll 8
    for (int j = 0; j < 512; ++j) r += (ch[j] > mine) ? 1u : 0u;
    if (me < nc && r) atomicAdd(&rank[me], r);
}

__global__ void k_scatter(const u32* __restrict__ scal, const u64* __restrict__ cand,
                          const u32* __restrict__ rank, u64* __restrict__ sorted) {
    u32 nc = scal[5]; if (nc > CANDCAP) nc = CANDCAP;
    u32 t = blockIdx.x * 256u + threadIdx.x;
    if (t < nc) {
        u32 r = rank[t];
        if (r < (u32)KSEL) sorted[r] = cand[t];
    }
}

// ---------------- decode helpers ----------
__device__ __forceinline__ void decode_box(u64 cpack, const float* __restrict__ boxp,
                                           const float* __restrict__ anch, float b[7]) {
    u32 key = (u32)(cpack >> 32);
    u32 idx = ~((u32)(cpack & 0xFFFFFFFFull));
    if (key == 0u) idx = 0u;
    const float* a7 = anch + (size_t)idx * 7;
    const float* t7 = boxp + (size_t)idx * 7;
    float xa = a7[0], ya = a7[1], za = a7[2], wa = a7[3], la = a7[4], ha = a7[5], ra = a7[6];
    float xt = t7[0], yt = t7[1], zt = t7[2], wt = t7[3], lt_ = t7[4], ht = t7[5], rt = t7[6];
    za = za + ha * 0.5f;
    float diag = sqrtf(la * la + wa * wa);
    float xg = xt * diag + xa;
    float yg = yt * diag + ya;
    float zg = zt * ha + za;
    float lg = expf(lt_) * la;
    float wg = expf(wt) * wa;
    float hg = expf(ht) * ha;
    float rg = rt + ra;
    zg = zg - hg * 0.5f;
    b[0] = xg; b[1] = yg; b[2] = zg; b[3] = wg; b[4] = lg; b[5] = hg; b[6] = rg;
}

__device__ __forceinline__ float4 standup_box(const float b[7], float* areao) {
    float xg = b[0], yg = b[1], wg = b[3], lg = b[4], rg = b[6];
    float cc = cosf(rg), ss = sinf(rg);
    float dx = wg * 0.5f, dy = lg * 0.5f;
    const float sxs[4] = {-1.f, -1.f, 1.f, 1.f};
    const float sys[4] = {-1.f, 1.f, 1.f, -1.f};
    float minx = 1e30f, miny = 1e30f, maxx = -1e30f, maxy = -1e30f;
    #pragma unroll
    for (int k = 0; k < 4; ++k) {
        float cx = dx * sxs[k], cy = dy * sys[k];
        float px = cx * cc + cy * ss;
        float py = cx * (-ss) + cy * cc;
        px = px + xg; py = py + yg;
        minx = fminf(minx, px); maxx = fmaxf(maxx, px);
        miny = fminf(miny, py); maxy = fmaxf(maxy, py);
    }
    *areao = (maxx - minx) * (maxy - miny);
    return make_float4(minx, miny, maxx, maxy);
}

// decode + standup once per selected box
__global__ void k_decode(const u64* __restrict__ sel2, const float* __restrict__ boxp,
                         const float* __restrict__ anch, float4* __restrict__ bb,
                         float* __restrict__ area) {
    int r = blockIdx.x * blockDim.x + threadIdx.x;
    if (r >= KSEL) return;
    float b[7];
    decode_box(sel2[r], boxp, anch, b);
    float a;
    bb[r] = standup_box(b, &a);
    area[r] = a;
}

// 64x64 IoU mask tile + sparse suppression lists (rank i -> ranks j>i, IoU>0.5).
__global__ __launch_bounds__(64) void k_mask(const float4* __restrict__ bb,
                                             const float* __restrict__ area,
                                             u64* __restrict__ mask,
                                             u32* __restrict__ sup_cnt,
                                             u32* __restrict__ sup_ent) {
    int t = threadIdx.x;
    int rb = blockIdx.y, cb = blockIdx.x;
    int i = rb * 64 + t;
    if (cb < rb) { mask[(size_t)i * 64 + cb] = 0ull; return; }
    __shared__ float4 ob[64];
    __shared__ float oa[64];
    int jg0 = cb * 64;
    ob[t] = bb[jg0 + t];
    oa[t] = area[jg0 + t];
    __syncthreads();
    float4 m4 = bb[i];
    float ma = area[i];
    u64 bits = 0;
    for (int j = 0; j < 64; ++j) {
        int jg = jg0 + j;
        if (jg == i) continue;
        float4 o = ob[j];
        float ltx = fmaxf(m4.x, o.x), lty = fmaxf(m4.y, o.y);
        float rbx = fminf(m4.z, o.z), rby = fminf(m4.w, o.w);
        float w = fmaxf(rbx - ltx, 0.0f), h = fmaxf(rby - lty, 0.0f);
        float inter = w * h;
        float iou = inter / (ma + oa[j] - inter + 1e-8f);
        if (iou > 0.5f) bits |= (1ULL << j);
    }
    mask[(size_t)i * 64 + cb] = bits;
    u64 bset = bits;
    while (bset) {
        int j = (int)__builtin_ctzll(bset);
        bset &= bset - 1;
        int jg = jg0 + j;
        if (jg > i) {
            u32 p = atomicAdd(&sup_cnt[i], 1u);
            if (p < SUPCAP) sup_ent[(size_t)i * SUPCAP + p] = (u32)jg;
        }
    }
}

// 4-wave window-256 greedy NMS over sparse suppression lists. ~2 rounds total.
__global__ __launch_bounds__(256, 1) void k_serial(const u64* __restrict__ mask,
                                                   const u32* __restrict__ sup_cnt,
                                                   const u32* __restrict__ sup_ent,
                                                   u32* __restrict__ keep_list,
                                                   u32* __restrict__ scal) {
    int t = threadIdx.x;
    int lane = t & 63;
    int wave = t >> 6;
    __shared__ u64 ls_avail[64];
    __shared__ u32 ls_excl[64];
    __shared__ int ls_cand[WW];
    __shared__ u64 ls_m[WW][4];
    __shared__ u64 ls_wv[4];
    __shared__ u32 ls_ovf[OVFCAP];
    __shared__ u32 ls_novf;

    if (t < 64) {
        u32 nvt = scal[9];
        u32 nv = (nvt < (u32)KSEL) ? nvt : (u32)KSEL;
        int lo = t * 64;
        u64 a;
        if ((int)nv >= lo + 64) a = ~0ull;
        else if ((int)nv <= lo) a = 0ull;
        else a = (((u64)1) << (nv - lo)) - 1ull;
        ls_avail[t] = a;
    }
    __syncthreads();

    int cnt = 0;
    for (;;) {
        // --- init per-round state ---
        ls_m[t][0] = 0; ls_m[t][1] = 0; ls_m[t][2] = 0; ls_m[t][3] = 0;
        ls_cand[t] = -1;
        if (t == 0) ls_novf = 0;
        __syncthreads();
        // --- selection (wave 0): prefix + parallel bit-walks ---
        if (t < 64) {
            u64 avail = ls_avail[t];
            u32 pc = (u32)__popcll(avail);
            u32 pre = pc;
            #pragma unroll
            for (int off = 1; off < 64; off <<= 1) {
                u32 y = __shfl_up(pre, (unsigned)off);
                if (lane >= off) pre += y;
            }
            u32 excl = pre - pc;
            ls_excl[t] = excl;
            if (pc && excl < (u32)WW) {
                u64 a = avail;
                u32 o = excl;
                while (a && o < (u32)WW) {
                    int b = (int)__builtin_ctzll(a);
                    a &= a - 1;
                    ls_cand[o++] = t * 64 + b;
                }
            }
        }
        __syncthreads();
        int cj = ls_cand[t];
        bool valid = cj >= 0;
        {
            u64 wvb = __ballot(valid);
            if (lane == 0) ls_wv[wave] = wvb;
        }
        if (ls_cand[0] < 0) break;
        // --- fetch list + count CONCURRENTLY (no serial dependency) ---
        int cs = valid ? cj : 0;
        const uint4* ep = (const uint4*)(sup_ent + (size_t)cs * SUPCAP);
        uint4 e0 = ep[0], e1 = ep[1], e2 = ep[2], e3 = ep[3];
        u32 scnt = sup_cnt[cs];
        if (!valid) scnt = 0;
        u32 ecap = (scnt < (u32)SUPCAP) ? scnt : (u32)SUPCAP;
        u32 ent[SUPCAP] = {e0.x, e0.y, e0.z, e0.w, e1.x, e1.y, e1.z, e1.w,
                           e2.x, e2.y, e2.z, e2.w, e3.x, e3.y, e3.z, e3.w};
        bool ovf = valid && (scnt > (u32)SUPCAP);
        // --- row build: my slot t suppresses slot(r) -> set bit t in ls_m[slot] ---
        #pragma unroll
        for (int e = 0; e < SUPCAP; ++e) {
            u32 r = ent[e];
            if ((u32)e < ecap && r < (u32)KSEL) {
                u64 aw = ls_avail[r >> 6];
                if ((aw >> (r & 63)) & 1ull) {
                    u64 below = (r & 63) ? (aw & ((1ull << (r & 63)) - 1ull)) : 0ull;
                    u32 slot = ls_excl[r >> 6] + (u32)__popcll(below);
                    if (slot < (u32)WW)
                        atomicOr(&ls_m[slot][t >> 6], 1ull << (t & 63));
                }
            }
        }
        if (ovf) { u32 p = atomicAdd(&ls_novf, 1u); if (p < OVFCAP) ls_ovf[p] = (u32)t; }
        __syncthreads();
        // --- overflow fallback: dense-row conversion (rare; exact) ---
        u32 novf = ls_novf; if (novf > OVFCAP) novf = OVFCAP;
        for (u32 oi = 0; oi < novf; ++oi) {
            int s = (int)ls_ovf[oi];
            int ci = ls_cand[s];
            if (t < 64) {
                u64 w = mask[(size_t)ci * 64 + t] & ls_avail[t];
                while (w) {
                    int b = (int)__builtin_ctzll(w);
                    w &= w - 1;
                    u32 r = (u32)(t * 64 + b);
                    u64 aw = ls_avail[t];
                    u64 below = b ? (aw & ((1ull << b) - 1ull)) : 0ull;
                    u32 slot = ls_excl[t] + (u32)__popcll(below);
                    if (slot < (u32)WW && slot != (u32)s)
                        atomicOr(&ls_m[slot][s >> 6], 1ull << (s & 63));
                    (void)r;
                }
            }
        }
        __syncthreads();
        // --- replicated ordered commit: register bitmaps, static block indexing ---
        u64 wv0 = ls_wv[0], wv1 = ls_wv[1], wv2 = ls_wv[2], wv3 = ls_wv[3];
        u64 c0 = 0, c1 = 0, c2 = 0, c3 = 0;
        bool stop = false;
        #pragma unroll
        for (int blk = 0; blk < 4; ++blk) {
            u64 wvb = (blk == 0) ? wv0 : (blk == 1) ? wv1 : (blk == 2) ? wv2 : wv3;
            for (int j2 = 0; j2 < 64; ++j2) {
                if (!((wvb >> j2) & 1ull)) continue;
                int j = blk * 64 + j2;
                u64 m0 = ls_m[j][0], m1 = ls_m[j][1], m2 = ls_m[j][2], m3 = ls_m[j][3];
                u64 sup = (m0 & c0) | (m1 & c1) | (m2 & c2) | (m3 & c3);
                if (sup) continue;
                if (t == 0 && cnt < POST) keep_list[cnt] = (u32)ls_cand[j];
                if (blk == 0) c0 |= 1ull << j2;
                else if (blk == 1) c1 |= 1ull << j2;
                else if (blk == 2) c2 |= 1ull << j2;
                else c3 |= 1ull << j2;
                cnt++;
                if (cnt >= POST) { stop = true; break; }
            }
            if (stop) break;
        }
        if (stop) break;
        // --- apply: committed slots clear their targets + own bit ---
        {
            u64 myc = (t < 64) ? c0 : (t < 128) ? c1 : (t < 192) ? c2 : c3;
            bool amC = valid && ((myc >> (t & 63)) & 1ull);
            if (amC) {
                #pragma unroll
                for (int e = 0; e < SUPCAP; ++e) {
                    u32 r = ent[e];
                    if ((u32)e < ecap && r < (u32)KSEL)
                        atomicAnd(&ls_avail[r >> 6], ~(1ull << (r & 63)));
                }
                atomicAnd(&ls_avail[cj >> 6], ~(1ull << (cj & 63)));
            }
            for (u32 oi = 0; oi < novf; ++oi) {
                int s = (int)ls_ovf[oi];
                u64 sc = (s < 64) ? c0 : (s < 128) ? c1 : (s < 192) ? c2 : c3;
                if ((sc >> (s & 63)) & 1ull) {
                    int ci = ls_cand[s];
                    if (t < 64) {
                        u64 w = mask[(size_t)ci * 64 + t];
                        if (w) atomicAnd(&ls_avail[t], ~w);
                    }
                }
            }
        }
        __syncthreads();
    }
    if (t == 0) scal[7] = (u32)(cnt < POST ? cnt : POST);
}

__global__ void k_final(const u32* __restrict__ scal, const u32* __restrict__ keep_list,
                        const u64* __restrict__ sel2, const float* __restrict__ boxp,
                        const float* __restrict__ anch, const float* __restrict__ cls,
                        const float* __restrict__ dirp, float* __restrict__ out) {
    int t = blockIdx.x * blockDim.x + threadIdx.x;
    if (t >= POST) return;
    u32 m = scal[7];
    float* ob = out;
    float* os = out + POST * 7;
    float* ol = os + POST;
    float* ov = ol + POST;
    if (t < (int)m) {
        u32 r = keep_list[t];
        u64 cp = sel2[r];
        u32 key = (u32)(cp >> 32);
        u32 i = ~((u32)(cp & 0xFFFFFFFFull));
        float b[7];
        decode_box(cp, boxp, anch, b);
        float d0 = dirp[(size_t)i * 2], d1 = dirp[(size_t)i * 2 + 1];
        int dl = (d1 > d0) ? 1 : 0;
        int pos = (b[6] > 0.0f) ? 1 : 0;
        if (pos ^ dl) b[6] = b[6] + 3.14159265358979323846f;
        for (int q = 0; q < 7; ++q) ob[(size_t)t * 7 + q] = b[q];
        os[t] = __uint_as_float(key);
        float s0 = 1.0f / (1.0f + expf(-cls[(size_t)i * 3]));
        float s1 = 1.0f / (1.0f + expf(-cls[(size_t)i * 3 + 1]));
        float s2 = 1.0f / (1.0f + expf(-cls[(size_t)i * 3 + 2]));
        int lab = 0; float best = s0;
        if (s1 > best) { lab = 1; best = s1; }
        if (s2 > best) { lab = 2; }
        ol[t] = (float)lab;
        ov[t] = 1.0f;
    } else {
        for (int q = 0; q < 7; ++q) ob[(size_t)t * 7 + q] = 0.0f;
        os[t] = 0.0f;
        ol[t] = -1.0f;
        ov[t] = 0.0f;
    }
}

extern "C" void kernel_launch(void* const* d_in, const int* in_sizes, int n_in,
                              void* d_out, int out_size, void* d_ws, size_t ws_size,
                              hipStream_t stream) {
    const float* box_preds = (const float*)d_in[0];
    const float* cls_preds = (const float*)d_in[1];
    const float* dir_preds = (const float*)d_in[2];
    const float* anchors   = (const float*)d_in[3];
    float* out = (float*)d_out;

    unsigned char* w = (unsigned char*)d_ws;
    size_t off = 0;
    auto nxt = [&](size_t bytes) -> void* {
        void* p = (void*)(w + off);
        off = (off + bytes + 255) & ~(size_t)255;
        return p;
    };
    // memset region (contiguous): hist1 | scal | sel2 | rank | sup_cnt
    u32* hist1     = (u32*)nxt(H1BINS * 4);            //  4096 B
    u32* scal      = (u32*)nxt(64 * 4);                //   256 B
    u64* sel2      = (u64*)nxt((size_t)KSEL * 8);      // 32768 B
    u32* rank      = (u32*)nxt((size_t)CANDCAP * 4);   // 65536 B
    u32* sup_cnt   = (u32*)nxt((size_t)KSEL * 4);      // 16384 B
    u64* cand      = (u64*)nxt((size_t)CANDCAP * 8);
    u64* mask      = (u64*)nxt((size_t)KSEL * 64 * 8);
    u32* sup_ent   = (u32*)nxt((size_t)KSEL * SUPCAP * 4);
    u32* keep_list = (u32*)nxt(512 * 4);
    float4* bb     = (float4*)nxt((size_t)KSEL * 16);
    float* area    = (float*)nxt((size_t)KSEL * 4);
    u32* keys      = (u32*)nxt((size_t)N_ANCH * 4);

    hipMemsetAsync(hist1, 0,
                   (size_t)H1BINS * 4 + 256 + (size_t)KSEL * 8 + (size_t)CANDCAP * 4
                   + (size_t)KSEL * 4,
                   stream);

    k_keys<<<(NQUAD + 1023) / 1024, 1024, 0, stream>>>((const float4*)cls_preds,
                                                       (uint4*)keys, hist1);
    k_scan1<<<1, 1024, 0, stream>>>(hist1, scal);
    k_compact<<<(NQUAD + 255) / 256, 256, 0, stream>>>((const uint4*)keys, scal, cand);
    dim3 rg(CANDCAP / 256, CANDCAP / 512);
    k_rankpart<<<rg, 256, 0, stream>>>(scal, cand, rank);
    k_scatter<<<CANDCAP / 256, 256, 0, stream>>>(scal, cand, rank, sel2);
    k_decode<<<KSEL / 256, 256, 0, stream>>>(sel2, box_preds, anchors, bb, area);
    dim3 mg(64, 64);
    k_mask<<<mg, 64, 0, stream>>>(bb, area, mask, sup_cnt, sup_ent);
    k_serial<<<1, 256, 0, stream>>>(mask, sup_cnt, sup_ent, keep_list, scal);
    k_final<<<2, 256, 0, stream>>>(scal, keep_list, sel2, box_preds, anchors, cls_preds, dir_preds, out);
}

// Round 15
// 86.071 us; speedup vs baseline: 2.1243x; 1.5538x over previous
//
#include <hip/hip_runtime.h>

#pragma clang fp contract(off)

#define N_ANCH 321408
#define NQUAD (N_ANCH / 4)
#define KSEL 4096
#define POST 300
#define H1BINS 1024
#define H1BASE 0x3D40u   // remap: bin = (k>>16) - H1BASE + 1 ; bin 0 = invalid (k==0)
#define CANDCAP 16384
#define SUPCAP 16        // max stored suppression targets per row; overflow -> dense fallback
#define WW 256           // NMS window width (4 waves)
#define OVFCAP 32

typedef unsigned int u32;
typedef unsigned long long u64;

__device__ __forceinline__ u32 key_of(float m) {
    float s = 1.0f / (1.0f + expf(-m));
    return (s >= 0.05f) ? __float_as_uint(s) : 0u;
}

// ---------------- scoring (vectorized 4 anchors/thread) + coarse histogram ----------------
__global__ __launch_bounds__(1024) void k_keys(const float4* __restrict__ cls4,
                                               uint4* __restrict__ keys4,
                                               u32* __restrict__ hist) {
    __shared__ u32 h0[H1BINS], h1[H1BINS];
    int t = threadIdx.x;
    h0[t] = 0; h1[t] = 0;
    __syncthreads();
    int q = blockIdx.x * 1024 + t;
    if (q < NQUAD) {
        float4 a = cls4[q * 3], b = cls4[q * 3 + 1], d = cls4[q * 3 + 2];
        u32 k0 = key_of(fmaxf(a.x, fmaxf(a.y, a.z)));
        u32 k1 = key_of(fmaxf(a.w, fmaxf(b.x, b.y)));
        u32 k2 = key_of(fmaxf(b.z, fmaxf(b.w, d.x)));
        u32 k3 = key_of(fmaxf(d.y, fmaxf(d.z, d.w)));
        keys4[q] = make_uint4(k0, k1, k2, k3);
        u32* hp = (t & 1) ? h1 : h0;
        atomicAdd(&hp[k0 ? ((k0 >> 16) - H1BASE + 1u) : 0u], 1u);
        atomicAdd(&hp[k1 ? ((k1 >> 16) - H1BASE + 1u) : 0u], 1u);
        atomicAdd(&hp[k2 ? ((k2 >> 16) - H1BASE + 1u) : 0u], 1u);
        atomicAdd(&hp[k3 ? ((k3 >> 16) - H1BASE + 1u) : 0u], 1u);
    }
    __syncthreads();
    u32 c = h0[t] + h1[t];
    if (c) atomicAdd(&hist[t], c);
}

// scan 1024 coarse bins from the top: crossing bin + total valid count
__global__ __launch_bounds__(1024) void k_scan1(const u32* __restrict__ hist, u32* scal) {
    __shared__ u32 sh[1024];
    int t = threadIdx.x;
    int b = 1023 - t;                 // descending bins
    u32 s = hist[b];
    sh[t] = s;
    __syncthreads();
    for (int off = 1; off < 1024; off <<= 1) {
        u32 x = sh[t];
        u32 y = (t >= off) ? sh[t - off] : 0u;
        __syncthreads();
        sh[t] = x + y;
        __syncthreads();
    }
    u32 incl = sh[t];
    u32 excl = incl - s;
    if (excl < 4096u && incl >= 4096u) {
        scal[8] = (b > 0) ? (u32)(b - 1) + H1BASE : 0u;   // actual upper-16 of crossing bin
    }
    if (t == 1023) scal[9] = incl - s;                    // total valid (minus bin 0)
}

// all candidates in bins >= crossing bin; wave-aggregated atomic, vectorized reads
__global__ __launch_bounds__(256) void k_compact(const uint4* __restrict__ keys4,
                                                 u32* scal, u64* __restrict__ cand) {
    int q = blockIdx.x * 256 + threadIdx.x;
    bool act = q < NQUAD;
    uint4 kv = act ? keys4[q] : make_uint4(0, 0, 0, 0);
    u32 thr16 = scal[8];
    int lane = threadIdx.x & 63;
    u32 i0 = (u32)q * 4u;
    bool p0 = kv.x && (kv.x >> 16) >= thr16;
    bool p1 = kv.y && (kv.y >> 16) >= thr16;
    bool p2 = kv.z && (kv.z >> 16) >= thr16;
    bool p3 = kv.w && (kv.w >> 16) >= thr16;
    u64 b0 = __ballot(p0), b1 = __ballot(p1), b2 = __ballot(p2), b3 = __ballot(p3);
    u32 n0 = (u32)__popcll(b0), n1 = (u32)__popcll(b1), n2 = (u32)__popcll(b2);
    u32 nw = n0 + n1 + n2 + (u32)__popcll(b3);
    u32 base = 0;
    if (lane == 0 && nw) base = atomicAdd(&scal[5], nw);
    base = (u32)__shfl((int)base, 0);
    u64 lt = (lane == 0) ? 0ull : (~0ull >> (64 - lane));
    if (p0) { u32 p = base + (u32)__popcll(b0 & lt);
              if (p < CANDCAP) cand[p] = (((u64)kv.x) << 32) | (u32)(~(i0 + 0)); }
    if (p1) { u32 p = base + n0 + (u32)__popcll(b1 & lt);
              if (p < CANDCAP) cand[p] = (((u64)kv.y) << 32) | (u32)(~(i0 + 1)); }
    if (p2) { u32 p = base + n0 + n1 + (u32)__popcll(b2 & lt);
              if (p < CANDCAP) cand[p] = (((u64)kv.z) << 32) | (u32)(~(i0 + 2)); }
    if (p3) { u32 p = base + n0 + n1 + n2 + (u32)__popcll(b3 & lt);
              if (p < CANDCAP) cand[p] = (((u64)kv.w) << 32) | (u32)(~(i0 + 3)); }
}

// 2D partial rank-by-counting
__global__ __launch_bounds__(256) void k_rankpart(const u32* __restrict__ scal,
                                                  const u64* __restrict__ cand,
                                                  u32* __restrict__ rank) {
    __shared__ u64 ch[512];
    u32 nc = scal[5]; if (nc > CANDCAP) nc = CANDCAP;
    u32 cb = blockIdx.x * 256u;
    u32 jb = blockIdx.y * 512u;
    if (cb >= nc || jb >= nc) return;
    u32 t = threadIdx.x;
    for (u32 j = t; j < 512u; j += 256u)
        ch[j] = (jb + j < nc) ? cand[jb + j] : 0ull;
    __syncthreads();
    u32 me = cb + t;
    u64 mine = (me < nc) ? cand[me] : ~0ull;
    u32 r = 0;
    #pragma unroll 8
    for (int j = 0; j < 512; ++j) r += (ch[j] > mine) ? 1u : 0u;
    if (me < nc && r) atomicAdd(&rank[me], r);
}

__global__ void k_scatter(const u32* __restrict__ scal, const u64* __restrict__ cand,
                          const u32* __restrict__ rank, u64* __restrict__ sorted) {
    u32 nc = scal[5]; if (nc > CANDCAP) nc = CANDCAP;
    u32 t = blockIdx.x * 256u + threadIdx.x;
    if (t < nc) {
        u32 r = rank[t];
        if (r < (u32)KSEL) sorted[r] = cand[t];
    }
}

// ---------------- decode helpers ----------
__device__ __forceinline__ void decode_box(u64 cpack, const float* __restrict__ boxp,
                                           const float* __restrict__ anch, float b[7]) {
    u32 key = (u32)(cpack >> 32);
    u32 idx = ~((u32)(cpack & 0xFFFFFFFFull));
    if (key == 0u) idx = 0u;
    const float* a7 = anch + (size_t)idx * 7;
    const float* t7 = boxp + (size_t)idx * 7;
    float xa = a7[0], ya = a7[1], za = a7[2], wa = a7[3], la = a7[4], ha = a7[5], ra = a7[6];
    float xt = t7[0], yt = t7[1], zt = t7[2], wt = t7[3], lt_ = t7[4], ht = t7[5], rt = t7[6];
    za = za + ha * 0.5f;
    float diag = sqrtf(la * la + wa * wa);
    float xg = xt * diag + xa;
    float yg = yt * diag + ya;
    float zg = zt * ha + za;
    float lg = expf(lt_) * la;
    float wg = expf(wt) * wa;
    float hg = expf(ht) * ha;
    float rg = rt + ra;
    zg = zg - hg * 0.5f;
    b[0] = xg; b[1] = yg; b[2] = zg; b[3] = wg; b[4] = lg; b[5] = hg; b[6] = rg;
}

__device__ __forceinline__ float4 standup_box(const float b[7], float* areao) {
    float xg = b[0], yg = b[1], wg = b[3], lg = b[4], rg = b[6];
    float cc = cosf(rg), ss = sinf(rg);
    float dx = wg * 0.5f, dy = lg * 0.5f;
    const float sxs[4] = {-1.f, -1.f, 1.f, 1.f};
    const float sys[4] = {-1.f, 1.f, 1.f, -1.f};
    float minx = 1e30f, miny = 1e30f, maxx = -1e30f, maxy = -1e30f;
    #pragma unroll
    for (int k = 0; k < 4; ++k) {
        float cx = dx * sxs[k], cy = dy * sys[k];
        float px = cx * cc + cy * ss;
        float py = cx * (-ss) + cy * cc;
        px = px + xg; py = py + yg;
        minx = fminf(minx, px); maxx = fmaxf(maxx, px);
        miny = fminf(miny, py); maxy = fmaxf(maxy, py);
    }
    *areao = (maxx - minx) * (maxy - miny);
    return make_float4(minx, miny, maxx, maxy);
}

// decode + standup once per selected box
__global__ void k_decode(const u64* __restrict__ sel2, const float* __restrict__ boxp,
                         const float* __restrict__ anch, float4* __restrict__ bb,
                         float* __restrict__ area) {
    int r = blockIdx.x * blockDim.x + threadIdx.x;
    if (r >= KSEL) return;
    float b[7];
    decode_box(sel2[r], boxp, anch, b);
    float a;
    bb[r] = standup_box(b, &a);
    area[r] = a;
}

// 64x64 IoU mask tile + sparse suppression lists (rank i -> ranks j>i, IoU>0.5).
__global__ __launch_bounds__(64) void k_mask(const float4* __restrict__ bb,
                                             const float* __restrict__ area,
                                             u64* __restrict__ mask,
                                             u32* __restrict__ sup_cnt,
                                             u32* __restrict__ sup_ent) {
    int t = threadIdx.x;
    int rb = blockIdx.y, cb = blockIdx.x;
    int i = rb * 64 + t;
    if (cb < rb) { mask[(size_t)i * 64 + cb] = 0ull; return; }
    __shared__ float4 ob[64];
    __shared__ float oa[64];
    int jg0 = cb * 64;
    ob[t] = bb[jg0 + t];
    oa[t] = area[jg0 + t];
    __syncthreads();
    float4 m4 = bb[i];
    float ma = area[i];
    u64 bits = 0;
    for (int j = 0; j < 64; ++j) {
        int jg = jg0 + j;
        if (jg == i) continue;
        float4 o = ob[j];
        float ltx = fmaxf(m4.x, o.x), lty = fmaxf(m4.y, o.y);
        float rbx = fminf(m4.z, o.z), rby = fminf(m4.w, o.w);
        float w = fmaxf(rbx - ltx, 0.0f), h = fmaxf(rby - lty, 0.0f);
        float inter = w * h;
        float iou = inter / (ma + oa[j] - inter + 1e-8f);
        if (iou > 0.5f) bits |= (1ULL << j);
    }
    mask[(size_t)i * 64 + cb] = bits;
    u64 bset = bits;
    while (bset) {
        int j = (int)__builtin_ctzll(bset);
        bset &= bset - 1;
        int jg = jg0 + j;
        if (jg > i) {
            u32 p = atomicAdd(&sup_cnt[i], 1u);
            if (p < SUPCAP) sup_ent[(size_t)i * SUPCAP + p] = (u32)jg;
        }
    }
}

// 4-wave window-256 greedy NMS over sparse suppression lists.
// Commit phase: slots with no in-window suppressor (m==0, ~90%) auto-commit;
// only the few uncertain slots run the ordered sequential check.
__global__ __launch_bounds__(256, 1) void k_serial(const u64* __restrict__ mask,
                                                   const u32* __restrict__ sup_cnt,
                                                   const u32* __restrict__ sup_ent,
                                                   u32* __restrict__ keep_list,
                                                   u32* __restrict__ scal) {
    int t = threadIdx.x;
    int lane = t & 63;
    int wave = t >> 6;
    __shared__ u64 ls_avail[64];
    __shared__ u32 ls_excl[64];
    __shared__ int ls_cand[WW];
    __shared__ u64 ls_m[WW][4];
    __shared__ u64 ls_wv[4];
    __shared__ u64 ls_unc[4];
    __shared__ u32 ls_ovf[OVFCAP];
    __shared__ u32 ls_novf;

    if (t < 64) {
        u32 nvt = scal[9];
        u32 nv = (nvt < (u32)KSEL) ? nvt : (u32)KSEL;
        int lo = t * 64;
        u64 a;
        if ((int)nv >= lo + 64) a = ~0ull;
        else if ((int)nv <= lo) a = 0ull;
        else a = (((u64)1) << (nv - lo)) - 1ull;
        ls_avail[t] = a;
    }
    __syncthreads();

    int cnt = 0;
    for (;;) {
        // --- init per-round state ---
        ls_m[t][0] = 0; ls_m[t][1] = 0; ls_m[t][2] = 0; ls_m[t][3] = 0;
        ls_cand[t] = -1;
        if (t == 0) ls_novf = 0;
        __syncthreads();
        // --- selection (wave 0): prefix + parallel bit-walks ---
        if (t < 64) {
            u64 avail = ls_avail[t];
            u32 pc = (u32)__popcll(avail);
            u32 pre = pc;
            #pragma unroll
            for (int off = 1; off < 64; off <<= 1) {
                u32 y = __shfl_up(pre, (unsigned)off);
                if (lane >= off) pre += y;
            }
            u32 excl = pre - pc;
            ls_excl[t] = excl;
            if (pc && excl < (u32)WW) {
                u64 a = avail;
                u32 o = excl;
                while (a && o < (u32)WW) {
                    int b = (int)__builtin_ctzll(a);
                    a &= a - 1;
                    ls_cand[o++] = t * 64 + b;
                }
            }
        }
        __syncthreads();
        int cj = ls_cand[t];
        bool valid = cj >= 0;
        {
            u64 wvb = __ballot(valid);
            if (lane == 0) ls_wv[wave] = wvb;
        }
        if (ls_cand[0] < 0) break;
        // --- fetch list + count CONCURRENTLY (no serial dependency) ---
        int cs = valid ? cj : 0;
        const uint4* ep = (const uint4*)(sup_ent + (size_t)cs * SUPCAP);
        uint4 e0 = ep[0], e1 = ep[1], e2 = ep[2], e3 = ep[3];
        u32 scnt = sup_cnt[cs];
        if (!valid) scnt = 0;
        u32 ecap = (scnt < (u32)SUPCAP) ? scnt : (u32)SUPCAP;
        u32 ent[SUPCAP] = {e0.x, e0.y, e0.z, e0.w, e1.x, e1.y, e1.z, e1.w,
                           e2.x, e2.y, e2.z, e2.w, e3.x, e3.y, e3.z, e3.w};
        bool ovf = valid && (scnt > (u32)SUPCAP);
        // --- row build: my slot t suppresses slot(r) -> set bit t in ls_m[slot] ---
        #pragma unroll
        for (int e = 0; e < SUPCAP; ++e) {
            u32 r = ent[e];
            if ((u32)e < ecap && r < (u32)KSEL) {
                u64 aw = ls_avail[r >> 6];
                if ((aw >> (r & 63)) & 1ull) {
                    u64 below = (r & 63) ? (aw & ((1ull << (r & 63)) - 1ull)) : 0ull;
                    u32 slot = ls_excl[r >> 6] + (u32)__popcll(below);
                    if (slot < (u32)WW)
                        atomicOr(&ls_m[slot][t >> 6], 1ull << (t & 63));
                }
            }
        }
        if (ovf) { u32 p = atomicAdd(&ls_novf, 1u); if (p < OVFCAP) ls_ovf[p] = (u32)t; }
        __syncthreads();
        // --- overflow fallback: dense-row conversion (rare; exact) ---
        u32 novf = ls_novf; if (novf > OVFCAP) novf = OVFCAP;
        for (u32 oi = 0; oi < novf; ++oi) {
            int s = (int)ls_ovf[oi];
            int ci = ls_cand[s];
            if (t < 64) {
                u64 w = mask[(size_t)ci * 64 + t] & ls_avail[t];
                while (w) {
                    int b = (int)__builtin_ctzll(w);
                    w &= w - 1;
                    u64 aw = ls_avail[t];
                    u64 below = b ? (aw & ((1ull << b) - 1ull)) : 0ull;
                    u32 slot = ls_excl[t] + (u32)__popcll(below);
                    if (slot < (u32)WW && slot != (u32)s)
                        atomicOr(&ls_m[slot][s >> 6], 1ull << (s & 63));
                }
            }
        }
        __syncthreads();
        // --- commit phase 1: my own suppressor row; uncertain = nonzero ---
        u64 my0 = ls_m[t][0], my1 = ls_m[t][1], my2 = ls_m[t][2], my3 = ls_m[t][3];
        bool unc = valid && ((my0 | my1 | my2 | my3) != 0ull);
        {
            u64 ub = __ballot(unc);
            if (lane == 0) ls_unc[wave] = ub;
        }
        __syncthreads();
        // --- commit phase 2 (replicated): auto-commit certain, walk uncertain ---
        u64 wv0 = ls_wv[0], wv1 = ls_wv[1], wv2 = ls_wv[2], wv3 = ls_wv[3];
        u64 u0 = ls_unc[0], u1 = ls_unc[1], u2 = ls_unc[2], u3 = ls_unc[3];
        u64 c0 = wv0 & ~u0, c1 = wv1 & ~u1, c2 = wv2 & ~u2, c3 = wv3 & ~u3;
        #pragma unroll
        for (int blk = 0; blk < 4; ++blk) {
            u64 uw = (blk == 0) ? u0 : (blk == 1) ? u1 : (blk == 2) ? u2 : u3;
            while (uw) {
                int j2 = (int)__builtin_ctzll(uw);
                uw &= uw - 1;
                int j = blk * 64 + j2;
                u64 m0 = ls_m[j][0], m1 = ls_m[j][1], m2 = ls_m[j][2], m3 = ls_m[j][3];
                u64 sup = (m0 & c0) | (m1 & c1) | (m2 & c2) | (m3 & c3);
                if (!sup) {
                    if (blk == 0) c0 |= 1ull << j2;
                    else if (blk == 1) c1 |= 1ull << j2;
                    else if (blk == 2) c2 |= 1ull << j2;
                    else c3 |= 1ull << j2;
                }
            }
        }
        // --- parallel keep_list write (rank = popcount below own slot) ---
        u64 myc = (t < 64) ? c0 : (t < 128) ? c1 : (t < 192) ? c2 : c3;
        bool amC = valid && ((myc >> (t & 63)) & 1ull);
        {
            u32 rk = 0;
            if (wave > 0) rk += (u32)__popcll(c0);
            if (wave > 1) rk += (u32)__popcll(c1);
            if (wave > 2) rk += (u32)__popcll(c2);
            u64 below = (t & 63) ? (myc & ((1ull << (t & 63)) - 1ull)) : 0ull;
            rk += (u32)__popcll(below);
            if (amC && cnt + (int)rk < POST) keep_list[cnt + rk] = (u32)cj;
        }
        int tot = (int)(__popcll(c0) + __popcll(c1) + __popcll(c2) + __popcll(c3));
        if (cnt + tot >= POST) { cnt = POST; break; }
        cnt += tot;
        // --- apply: committed slots clear their targets + own bit ---
        if (amC) {
            #pragma unroll
            for (int e = 0; e < SUPCAP; ++e) {
                u32 r = ent[e];
                if ((u32)e < ecap && r < (u32)KSEL)
                    atomicAnd(&ls_avail[r >> 6], ~(1ull << (r & 63)));
            }
            atomicAnd(&ls_avail[cj >> 6], ~(1ull << (cj & 63)));
        }
        for (u32 oi = 0; oi < novf; ++oi) {
            int s = (int)ls_ovf[oi];
            u64 sc = (s < 64) ? c0 : (s < 128) ? c1 : (s < 192) ? c2 : c3;
            if ((sc >> (s & 63)) & 1ull) {
                int ci = ls_cand[s];
                if (t < 64) {
                    u64 w = mask[(size_t)ci * 64 + t];
                    if (w) atomicAnd(&ls_avail[t], ~w);
                }
            }
        }
        __syncthreads();
    }
    if (t == 0) scal[7] = (u32)(cnt < POST ? cnt : POST);
}

__global__ void k_final(const u32* __restrict__ scal, const u32* __restrict__ keep_list,
                        const u64* __restrict__ sel2, const float* __restrict__ boxp,
                        const float* __restrict__ anch, const float* __restrict__ cls,
                        const float* __restrict__ dirp, float* __restrict__ out) {
    int t = blockIdx.x * blockDim.x + threadIdx.x;
    if (t >= POST) return;
    u32 m = scal[7];
    float* ob = out;
    float* os = out + POST * 7;
    float* ol = os + POST;
    float* ov = ol + POST;
    if (t < (int)m) {
        u32 r = keep_list[t];
        u64 cp = sel2[r];
        u32 key = (u32)(cp >> 32);
        u32 i = ~((u32)(cp & 0xFFFFFFFFull));
        float b[7];
        decode_box(cp, boxp, anch, b);
        float d0 = dirp[(size_t)i * 2], d1 = dirp[(size_t)i * 2 + 1];
        int dl = (d1 > d0) ? 1 : 0;
        int pos = (b[6] > 0.0f) ? 1 : 0;
        if (pos ^ dl) b[6] = b[6] + 3.14159265358979323846f;
        for (int q = 0; q < 7; ++q) ob[(size_t)t * 7 + q] = b[q];
        os[t] = __uint_as_float(key);
        float s0 = 1.0f / (1.0f + expf(-cls[(size_t)i * 3]));
        float s1 = 1.0f / (1.0f + expf(-cls[(size_t)i * 3 + 1]));
        float s2 = 1.0f / (1.0f + expf(-cls[(size_t)i * 3 + 2]));
        int lab = 0; float best = s0;
        if (s1 > best) { lab = 1; best = s1; }
        if (s2 > best) { lab = 2; }
        ol[t] = (float)lab;
        ov[t] = 1.0f;
    } else {
        for (int q = 0; q < 7; ++q) ob[(size_t)t * 7 + q] = 0.0f;
        os[t] = 0.0f;
        ol[t] = -1.0f;
        ov[t] = 0.0f;
    }
}

extern "C" void kernel_launch(void* const* d_in, const int* in_sizes, int n_in,
                              void* d_out, int out_size, void* d_ws, size_t ws_size,
                              hipStream_t stream) {
    const float* box_preds = (const float*)d_in[0];
    const float* cls_preds = (const float*)d_in[1];
    const float* dir_preds = (const float*)d_in[2];
    const float* anchors   = (const float*)d_in[3];
    float* out = (float*)d_out;

    unsigned char* w = (unsigned char*)d_ws;
    size_t off = 0;
    auto nxt = [&](size_t bytes) -> void* {
        void* p = (void*)(w + off);
        off = (off + bytes + 255) & ~(size_t)255;
        return p;
    };
    // memset region (contiguous): hist1 | scal | sel2 | rank | sup_cnt
    u32* hist1     = (u32*)nxt(H1BINS * 4);            //  4096 B
    u32* scal      = (u32*)nxt(64 * 4);                //   256 B
    u64* sel2      = (u64*)nxt((size_t)KSEL * 8);      // 32768 B
    u32* rank      = (u32*)nxt((size_t)CANDCAP * 4);   // 65536 B
    u32* sup_cnt   = (u32*)nxt((size_t)KSEL * 4);      // 16384 B
    u64* cand      = (u64*)nxt((size_t)CANDCAP * 8);
    u64* mask      = (u64*)nxt((size_t)KSEL * 64 * 8);
    u32* sup_ent   = (u32*)nxt((size_t)KSEL * SUPCAP * 4);
    u32* keep_list = (u32*)nxt(512 * 4);
    float4* bb     = (float4*)nxt((size_t)KSEL * 16);
    float* area    = (float*)nxt((size_t)KSEL * 4);
    u32* keys      = (u32*)nxt((size_t)N_ANCH * 4);

    hipMemsetAsync(hist1, 0,
                   (size_t)H1BINS * 4 + 256 + (size_t)KSEL * 8 + (size_t)CANDCAP * 4
                   + (size_t)KSEL * 4,
                   stream);

    k_keys<<<(NQUAD + 1023) / 1024, 1024, 0, stream>>>((const float4*)cls_preds,
                                                       (uint4*)keys, hist1);
    k_scan1<<<1, 1024, 0, stream>>>(hist1, scal);
    k_compact<<<(NQUAD + 255) / 256, 256, 0, stream>>>((const uint4*)keys, scal, cand);
    dim3 rg(CANDCAP / 256, CANDCAP / 512);
    k_rankpart<<<rg, 256, 0, stream>>>(scal, cand, rank);
    k_scatter<<<CANDCAP / 256, 256, 0, stream>>>(scal, cand, rank, sel2);
    k_decode<<<KSEL / 256, 256, 0, stream>>>(sel2, box_preds, anchors, bb, area);
    dim3 mg(64, 64);
    k_mask<<<mg, 64, 0, stream>>>(bb, area, mask, sup_cnt, sup_ent);
    k_serial<<<1, 256, 0, stream>>>(mask, sup_cnt, sup_ent, keep_list, scal);
    k_final<<<2, 256, 0, stream>>>(scal, keep_list, sel2, box_preds, anchors, cls_preds, dir_preds, out);
}

// Round 16
// 85.063 us; speedup vs baseline: 2.1495x; 1.0119x over previous
//
#include <hip/hip_runtime.h>

#pragma clang fp contract(off)

#define N_ANCH 321408
#define NQUAD (N_ANCH / 4)
#define KSEL 4096
#define POST 300
#define H1BINS 1024
#define H1BASE 0x3D40u   // remap: bin = (k>>16) - H1BASE + 1 ; bin 0 = invalid (k==0)
#define CANDCAP 16384
#define SUPCAP 16        // max stored suppression targets per row; overflow -> dense fallback
#define WW 256           // NMS window width (4 waves)
#define OVFCAP 32
// zero region: hist1(4096) + scal(256) + sel2(32768) + rank(65536) + sup_cnt(16384)
#define ZERO_BYTES (4096 + 256 + 32768 + 65536 + 16384)
#define ZERO_U4 (ZERO_BYTES / 16)

typedef unsigned int u32;
typedef unsigned long long u64;

// ---------------- zero the accumulator region (replaces pathological runtime fill) ----
__global__ void k_zero(uint4* __restrict__ p) {
    int i = blockIdx.x * 256 + threadIdx.x;
    if (i < ZERO_U4) p[i] = make_uint4(0, 0, 0, 0);
}

__device__ __forceinline__ u32 key_of(float m) {
    float s = 1.0f / (1.0f + expf(-m));
    return (s >= 0.05f) ? __float_as_uint(s) : 0u;
}

// ---------------- scoring (vectorized 4 anchors/thread) + coarse histogram ----------------
__global__ __launch_bounds__(1024) void k_keys(const float4* __restrict__ cls4,
                                               uint4* __restrict__ keys4,
                                               u32* __restrict__ hist) {
    __shared__ u32 h0[H1BINS], h1[H1BINS];
    int t = threadIdx.x;
    h0[t] = 0; h1[t] = 0;
    __syncthreads();
    int q = blockIdx.x * 1024 + t;
    if (q < NQUAD) {
        float4 a = cls4[q * 3], b = cls4[q * 3 + 1], d = cls4[q * 3 + 2];
        u32 k0 = key_of(fmaxf(a.x, fmaxf(a.y, a.z)));
        u32 k1 = key_of(fmaxf(a.w, fmaxf(b.x, b.y)));
        u32 k2 = key_of(fmaxf(b.z, fmaxf(b.w, d.x)));
        u32 k3 = key_of(fmaxf(d.y, fmaxf(d.z, d.w)));
        keys4[q] = make_uint4(k0, k1, k2, k3);
        u32* hp = (t & 1) ? h1 : h0;
        atomicAdd(&hp[k0 ? ((k0 >> 16) - H1BASE + 1u) : 0u], 1u);
        atomicAdd(&hp[k1 ? ((k1 >> 16) - H1BASE + 1u) : 0u], 1u);
        atomicAdd(&hp[k2 ? ((k2 >> 16) - H1BASE + 1u) : 0u], 1u);
        atomicAdd(&hp[k3 ? ((k3 >> 16) - H1BASE + 1u) : 0u], 1u);
    }
    __syncthreads();
    u32 c = h0[t] + h1[t];
    if (c) atomicAdd(&hist[t], c);
}

// scan 1024 coarse bins from the top: crossing bin + total valid count
__global__ __launch_bounds__(1024) void k_scan1(const u32* __restrict__ hist, u32* scal) {
    __shared__ u32 sh[1024];
    int t = threadIdx.x;
    int b = 1023 - t;                 // descending bins
    u32 s = hist[b];
    sh[t] = s;
    __syncthreads();
    for (int off = 1; off < 1024; off <<= 1) {
        u32 x = sh[t];
        u32 y = (t >= off) ? sh[t - off] : 0u;
        __syncthreads();
        sh[t] = x + y;
        __syncthreads();
    }
    u32 incl = sh[t];
    u32 excl = incl - s;
    if (excl < 4096u && incl >= 4096u) {
        scal[8] = (b > 0) ? (u32)(b - 1) + H1BASE : 0u;   // actual upper-16 of crossing bin
    }
    if (t == 1023) scal[9] = incl - s;                    // total valid (minus bin 0)
}

// all candidates in bins >= crossing bin; wave-aggregated atomic, vectorized reads
__global__ __launch_bounds__(256) void k_compact(const uint4* __restrict__ keys4,
                                                 u32* scal, u64* __restrict__ cand) {
    int q = blockIdx.x * 256 + threadIdx.x;
    bool act = q < NQUAD;
    uint4 kv = act ? keys4[q] : make_uint4(0, 0, 0, 0);
    u32 thr16 = scal[8];
    int lane = threadIdx.x & 63;
    u32 i0 = (u32)q * 4u;
    bool p0 = kv.x && (kv.x >> 16) >= thr16;
    bool p1 = kv.y && (kv.y >> 16) >= thr16;
    bool p2 = kv.z && (kv.z >> 16) >= thr16;
    bool p3 = kv.w && (kv.w >> 16) >= thr16;
    u64 b0 = __ballot(p0), b1 = __ballot(p1), b2 = __ballot(p2), b3 = __ballot(p3);
    u32 n0 = (u32)__popcll(b0), n1 = (u32)__popcll(b1), n2 = (u32)__popcll(b2);
    u32 nw = n0 + n1 + n2 + (u32)__popcll(b3);
    u32 base = 0;
    if (lane == 0 && nw) base = atomicAdd(&scal[5], nw);
    base = (u32)__shfl((int)base, 0);
    u64 lt = (lane == 0) ? 0ull : (~0ull >> (64 - lane));
    if (p0) { u32 p = base + (u32)__popcll(b0 & lt);
              if (p < CANDCAP) cand[p] = (((u64)kv.x) << 32) | (u32)(~(i0 + 0)); }
    if (p1) { u32 p = base + n0 + (u32)__popcll(b1 & lt);
              if (p < CANDCAP) cand[p] = (((u64)kv.y) << 32) | (u32)(~(i0 + 1)); }
    if (p2) { u32 p = base + n0 + n1 + (u32)__popcll(b2 & lt);
              if (p < CANDCAP) cand[p] = (((u64)kv.z) << 32) | (u32)(~(i0 + 2)); }
    if (p3) { u32 p = base + n0 + n1 + n2 + (u32)__popcll(b3 & lt);
              if (p < CANDCAP) cand[p] = (((u64)kv.w) << 32) | (u32)(~(i0 + 3)); }
}

// 2D partial rank-by-counting
__global__ __launch_bounds__(256) void k_rankpart(const u32* __restrict__ scal,
                                                  const u64* __restrict__ cand,
                                                  u32* __restrict__ rank) {
    __shared__ u64 ch[512];
    u32 nc = scal[5]; if (nc > CANDCAP) nc = CANDCAP;
    u32 cb = blockIdx.x * 256u;
    u32 jb = blockIdx.y * 512u;
    if (cb >= nc || jb >= nc) return;
    u32 t = threadIdx.x;
    for (u32 j = t; j < 512u; j += 256u)
        ch[j] = (jb + j < nc) ? cand[jb + j] : 0ull;
    __syncthreads();
    u32 me = cb + t;
    u64 mine = (me < nc) ? cand[me] : ~0ull;
    u32 r = 0;
    #pragma unroll 8
    for (int j = 0; j < 512; ++j) r += (ch[j] > mine) ? 1u : 0u;
    if (me < nc && r) atomicAdd(&rank[me], r);
}

__global__ void k_scatter(const u32* __restrict__ scal, const u64* __restrict__ cand,
                          const u32* __restrict__ rank, u64* __restrict__ sorted) {
    u32 nc = scal[5]; if (nc > CANDCAP) nc = CANDCAP;
    u32 t = blockIdx.x * 256u + threadIdx.x;
    if (t < nc) {
        u32 r = rank[t];
        if (r < (u32)KSEL) sorted[r] = cand[t];
    }
}

// ---------------- decode helpers ----------
__device__ __forceinline__ void decode_box(u64 cpack, const float* __restrict__ boxp,
                                           const float* __restrict__ anch, float b[7]) {
    u32 key = (u32)(cpack >> 32);
    u32 idx = ~((u32)(cpack & 0xFFFFFFFFull));
    if (key == 0u) idx = 0u;
    const float* a7 = anch + (size_t)idx * 7;
    const float* t7 = boxp + (size_t)idx * 7;
    float xa = a7[0], ya = a7[1], za = a7[2], wa = a7[3], la = a7[4], ha = a7[5], ra = a7[6];
    float xt = t7[0], yt = t7[1], zt = t7[2], wt = t7[3], lt_ = t7[4], ht = t7[5], rt = t7[6];
    za = za + ha * 0.5f;
    float diag = sqrtf(la * la + wa * wa);
    float xg = xt * diag + xa;
    float yg = yt * diag + ya;
    float zg = zt * ha + za;
    float lg = expf(lt_) * la;
    float wg = expf(wt) * wa;
    float hg = expf(ht) * ha;
    float rg = rt + ra;
    zg = zg - hg * 0.5f;
    b[0] = xg; b[1] = yg; b[2] = zg; b[3] = wg; b[4] = lg; b[5] = hg; b[6] = rg;
}

__device__ __forceinline__ float4 standup_box(const float b[7], float* areao) {
    float xg = b[0], yg = b[1], wg = b[3], lg = b[4], rg = b[6];
    float cc = cosf(rg), ss = sinf(rg);
    float dx = wg * 0.5f, dy = lg * 0.5f;
    const float sxs[4] = {-1.f, -1.f, 1.f, 1.f};
    const float sys[4] = {-1.f, 1.f, 1.f, -1.f};
    float minx = 1e30f, miny = 1e30f, maxx = -1e30f, maxy = -1e30f;
    #pragma unroll
    for (int k = 0; k < 4; ++k) {
        float cx = dx * sxs[k], cy = dy * sys[k];
        float px = cx * cc + cy * ss;
        float py = cx * (-ss) + cy * cc;
        px = px + xg; py = py + yg;
        minx = fminf(minx, px); maxx = fmaxf(maxx, px);
        miny = fminf(miny, py); maxy = fmaxf(maxy, py);
    }
    *areao = (maxx - minx) * (maxy - miny);
    return make_float4(minx, miny, maxx, maxy);
}

// decode + standup once per selected box
__global__ void k_decode(const u64* __restrict__ sel2, const float* __restrict__ boxp,
                         const float* __restrict__ anch, float4* __restrict__ bb,
                         float* __restrict__ area) {
    int r = blockIdx.x * blockDim.x + threadIdx.x;
    if (r >= KSEL) return;
    float b[7];
    decode_box(sel2[r], boxp, anch, b);
    float a;
    bb[r] = standup_box(b, &a);
    area[r] = a;
}

// 64x64 IoU mask tile + sparse suppression lists (rank i -> ranks j>i, IoU>0.5).
__global__ __launch_bounds__(64) void k_mask(const float4* __restrict__ bb,
                                             const float* __restrict__ area,
                                             u64* __restrict__ mask,
                                             u32* __restrict__ sup_cnt,
                                             u32* __restrict__ sup_ent) {
    int t = threadIdx.x;
    int rb = blockIdx.y, cb = blockIdx.x;
    int i = rb * 64 + t;
    if (cb < rb) { mask[(size_t)i * 64 + cb] = 0ull; return; }
    __shared__ float4 ob[64];
    __shared__ float oa[64];
    int jg0 = cb * 64;
    ob[t] = bb[jg0 + t];
    oa[t] = area[jg0 + t];
    __syncthreads();
    float4 m4 = bb[i];
    float ma = area[i];
    u64 bits = 0;
    for (int j = 0; j < 64; ++j) {
        int jg = jg0 + j;
        if (jg == i) continue;
        float4 o = ob[j];
        float ltx = fmaxf(m4.x, o.x), lty = fmaxf(m4.y, o.y);
        float rbx = fminf(m4.z, o.z), rby = fminf(m4.w, o.w);
        float w = fmaxf(rbx - ltx, 0.0f), h = fmaxf(rby - lty, 0.0f);
        float inter = w * h;
        float iou = inter / (ma + oa[j] - inter + 1e-8f);
        if (iou > 0.5f) bits |= (1ULL << j);
    }
    mask[(size_t)i * 64 + cb] = bits;
    u64 bset = bits;
    while (bset) {
        int j = (int)__builtin_ctzll(bset);
        bset &= bset - 1;
        int jg = jg0 + j;
        if (jg > i) {
            u32 p = atomicAdd(&sup_cnt[i], 1u);
            if (p < SUPCAP) sup_ent[(size_t)i * SUPCAP + p] = (u32)jg;
        }
    }
}

// 4-wave window-256 greedy NMS over sparse suppression lists.
// Commit phase: slots with no in-window suppressor (m==0, ~90%) auto-commit;
// only the few uncertain slots run the ordered sequential check.
__global__ __launch_bounds__(256, 1) void k_serial(const u64* __restrict__ mask,
                                                   const u32* __restrict__ sup_cnt,
                                                   const u32* __restrict__ sup_ent,
                                                   u32* __restrict__ keep_list,
                                                   u32* __restrict__ scal) {
    int t = threadIdx.x;
    int lane = t & 63;
    int wave = t >> 6;
    __shared__ u64 ls_avail[64];
    __shared__ u32 ls_excl[64];
    __shared__ int ls_cand[WW];
    __shared__ u64 ls_m[WW][4];
    __shared__ u64 ls_wv[4];
    __shared__ u64 ls_unc[4];
    __shared__ u32 ls_ovf[OVFCAP];
    __shared__ u32 ls_novf;

    if (t < 64) {
        u32 nvt = scal[9];
        u32 nv = (nvt < (u32)KSEL) ? nvt : (u32)KSEL;
        int lo = t * 64;
        u64 a;
        if ((int)nv >= lo + 64) a = ~0ull;
        else if ((int)nv <= lo) a = 0ull;
        else a = (((u64)1) << (nv - lo)) - 1ull;
        ls_avail[t] = a;
    }
    __syncthreads();

    int cnt = 0;
    for (;;) {
        // --- init per-round state ---
        ls_m[t][0] = 0; ls_m[t][1] = 0; ls_m[t][2] = 0; ls_m[t][3] = 0;
        ls_cand[t] = -1;
        if (t == 0) ls_novf = 0;
        __syncthreads();
        // --- selection (wave 0): prefix + parallel bit-walks ---
        if (t < 64) {
            u64 avail = ls_avail[t];
            u32 pc = (u32)__popcll(avail);
            u32 pre = pc;
            #pragma unroll
            for (int off = 1; off < 64; off <<= 1) {
                u32 y = __shfl_up(pre, (unsigned)off);
                if (lane >= off) pre += y;
            }
            u32 excl = pre - pc;
            ls_excl[t] = excl;
            if (pc && excl < (u32)WW) {
                u64 a = avail;
                u32 o = excl;
                while (a && o < (u32)WW) {
                    int b = (int)__builtin_ctzll(a);
                    a &= a - 1;
                    ls_cand[o++] = t * 64 + b;
                }
            }
        }
        __syncthreads();
        int cj = ls_cand[t];
        bool valid = cj >= 0;
        {
            u64 wvb = __ballot(valid);
            if (lane == 0) ls_wv[wave] = wvb;
        }
        if (ls_cand[0] < 0) break;
        // --- fetch list + count CONCURRENTLY (no serial dependency) ---
        int cs = valid ? cj : 0;
        const uint4* ep = (const uint4*)(sup_ent + (size_t)cs * SUPCAP);
        uint4 e0 = ep[0], e1 = ep[1], e2 = ep[2], e3 = ep[3];
        u32 scnt = sup_cnt[cs];
        if (!valid) scnt = 0;
        u32 ecap = (scnt < (u32)SUPCAP) ? scnt : (u32)SUPCAP;
        u32 ent[SUPCAP] = {e0.x, e0.y, e0.z, e0.w, e1.x, e1.y, e1.z, e1.w,
                           e2.x, e2.y, e2.z, e2.w, e3.x, e3.y, e3.z, e3.w};
        bool ovf = valid && (scnt > (u32)SUPCAP);
        // --- row build: my slot t suppresses slot(r) -> set bit t in ls_m[slot] ---
        #pragma unroll
        for (int e = 0; e < SUPCAP; ++e) {
            u32 r = ent[e];
            if ((u32)e < ecap && r < (u32)KSEL) {
                u64 aw = ls_avail[r >> 6];
                if ((aw >> (r & 63)) & 1ull) {
                    u64 below = (r & 63) ? (aw & ((1ull << (r & 63)) - 1ull)) : 0ull;
                    u32 slot = ls_excl[r >> 6] + (u32)__popcll(below);
                    if (slot < (u32)WW)
                        atomicOr(&ls_m[slot][t >> 6], 1ull << (t & 63));
                }
            }
        }
        if (ovf) { u32 p = atomicAdd(&ls_novf, 1u); if (p < OVFCAP) ls_ovf[p] = (u32)t; }
        __syncthreads();
        // --- overflow fallback: dense-row conversion (rare; exact) ---
        u32 novf = ls_novf; if (novf > OVFCAP) novf = OVFCAP;
        for (u32 oi = 0; oi < novf; ++oi) {
            int s = (int)ls_ovf[oi];
            int ci = ls_cand[s];
            if (t < 64) {
                u64 w = mask[(size_t)ci * 64 + t] & ls_avail[t];
                while (w) {
                    int b = (int)__builtin_ctzll(w);
                    w &= w - 1;
                    u64 aw = ls_avail[t];
                    u64 below = b ? (aw & ((1ull << b) - 1ull)) : 0ull;
                    u32 slot = ls_excl[t] + (u32)__popcll(below);
                    if (slot < (u32)WW && slot != (u32)s)
                        atomicOr(&ls_m[slot][s >> 6], 1ull << (s & 63));
                }
            }
        }
        __syncthreads();
        // --- commit phase 1: my own suppressor row; uncertain = nonzero ---
        u64 my0 = ls_m[t][0], my1 = ls_m[t][1], my2 = ls_m[t][2], my3 = ls_m[t][3];
        bool unc = valid && ((my0 | my1 | my2 | my3) != 0ull);
        {
            u64 ub = __ballot(unc);
            if (lane == 0) ls_unc[wave] = ub;
        }
        __syncthreads();
        // --- commit phase 2 (replicated): auto-commit certain, walk uncertain ---
        u64 wv0 = ls_wv[0], wv1 = ls_wv[1], wv2 = ls_wv[2], wv3 = ls_wv[3];
        u64 u0 = ls_unc[0], u1 = ls_unc[1], u2 = ls_unc[2], u3 = ls_unc[3];
        u64 c0 = wv0 & ~u0, c1 = wv1 & ~u1, c2 = wv2 & ~u2, c3 = wv3 & ~u3;
        #pragma unroll
        for (int blk = 0; blk < 4; ++blk) {
            u64 uw = (blk == 0) ? u0 : (blk == 1) ? u1 : (blk == 2) ? u2 : u3;
            while (uw) {
                int j2 = (int)__builtin_ctzll(uw);
                uw &= uw - 1;
                int j = blk * 64 + j2;
                u64 m0 = ls_m[j][0], m1 = ls_m[j][1], m2 = ls_m[j][2], m3 = ls_m[j][3];
                u64 sup = (m0 & c0) | (m1 & c1) | (m2 & c2) | (m3 & c3);
                if (!sup) {
                    if (blk == 0) c0 |= 1ull << j2;
                    else if (blk == 1) c1 |= 1ull << j2;
                    else if (blk == 2) c2 |= 1ull << j2;
                    else c3 |= 1ull << j2;
                }
            }
        }
        // --- parallel keep_list write (rank = popcount below own slot) ---
        u64 myc = (t < 64) ? c0 : (t < 128) ? c1 : (t < 192) ? c2 : c3;
        bool amC = valid && ((myc >> (t & 63)) & 1ull);
        {
            u32 rk = 0;
            if (wave > 0) rk += (u32)__popcll(c0);
            if (wave > 1) rk += (u32)__popcll(c1);
            if (wave > 2) rk += (u32)__popcll(c2);
            u64 below = (t & 63) ? (myc & ((1ull << (t & 63)) - 1ull)) : 0ull;
            rk += (u32)__popcll(below);
            if (amC && cnt + (int)rk < POST) keep_list[cnt + rk] = (u32)cj;
        }
        int tot = (int)(__popcll(c0) + __popcll(c1) + __popcll(c2) + __popcll(c3));
        if (cnt + tot >= POST) { cnt = POST; break; }
        cnt += tot;
        // --- apply: committed slots clear their targets + own bit ---
        if (amC) {
            #pragma unroll
            for (int e = 0; e < SUPCAP; ++e) {
                u32 r = ent[e];
                if ((u32)e < ecap && r < (u32)KSEL)
                    atomicAnd(&ls_avail[r >> 6], ~(1ull << (r & 63)));
            }
            atomicAnd(&ls_avail[cj >> 6], ~(1ull << (cj & 63)));
        }
        for (u32 oi = 0; oi < novf; ++oi) {
            int s = (int)ls_ovf[oi];
            u64 sc = (s < 64) ? c0 : (s < 128) ? c1 : (s < 192) ? c2 : c3;
            if ((sc >> (s & 63)) & 1ull) {
                int ci = ls_cand[s];
                if (t < 64) {
                    u64 w = mask[(size_t)ci * 64 + t];
                    if (w) atomicAnd(&ls_avail[t], ~w);
                }
            }
        }
        __syncthreads();
    }
    if (t == 0) scal[7] = (u32)(cnt < POST ? cnt : POST);
}

__global__ void k_final(const u32* __restrict__ scal, const u32* __restrict__ keep_list,
                        const u64* __restrict__ sel2, const float* __restrict__ boxp,
                        const float* __restrict__ anch, const float* __restrict__ cls,
                        const float* __restrict__ dirp, float* __restrict__ out) {
    int t = blockIdx.x * blockDim.x + threadIdx.x;
    if (t >= POST) return;
    u32 m = scal[7];
    float* ob = out;
    float* os = out + POST * 7;
    float* ol = os + POST;
    float* ov = ol + POST;
    if (t < (int)m) {
        u32 r = keep_list[t];
        u64 cp = sel2[r];
        u32 key = (u32)(cp >> 32);
        u32 i = ~((u32)(cp & 0xFFFFFFFFull));
        float b[7];
        decode_box(cp, boxp, anch, b);
        float d0 = dirp[(size_t)i * 2], d1 = dirp[(size_t)i * 2 + 1];
        int dl = (d1 > d0) ? 1 : 0;
        int pos = (b[6] > 0.0f) ? 1 : 0;
        if (pos ^ dl) b[6] = b[6] + 3.14159265358979323846f;
        for (int q = 0; q < 7; ++q) ob[(size_t)t * 7 + q] = b[q];
        os[t] = __uint_as_float(key);
        float s0 = 1.0f / (1.0f + expf(-cls[(size_t)i * 3]));
        float s1 = 1.0f / (1.0f + expf(-cls[(size_t)i * 3 + 1]));
        float s2 = 1.0f / (1.0f + expf(-cls[(size_t)i * 3 + 2]));
        int lab = 0; float best = s0;
        if (s1 > best) { lab = 1; best = s1; }
        if (s2 > best) { lab = 2; }
        ol[t] = (float)lab;
        ov[t] = 1.0f;
    } else {
        for (int q = 0; q < 7; ++q) ob[(size_t)t * 7 + q] = 0.0f;
        os[t] = 0.0f;
        ol[t] = -1.0f;
        ov[t] = 0.0f;
    }
}

extern "C" void kernel_launch(void* const* d_in, const int* in_sizes, int n_in,
                              void* d_out, int out_size, void* d_ws, size_t ws_size,
                              hipStream_t stream) {
    const float* box_preds = (const float*)d_in[0];
    const float* cls_preds = (const float*)d_in[1];
    const float* dir_preds = (const float*)d_in[2];
    const float* anchors   = (const float*)d_in[3];
    float* out = (float*)d_out;

    unsigned char* w = (unsigned char*)d_ws;
    size_t off = 0;
    auto nxt = [&](size_t bytes) -> void* {
        void* p = (void*)(w + off);
        off = (off + bytes + 255) & ~(size_t)255;
        return p;
    };
    // zero region (contiguous): hist1 | scal | sel2 | rank | sup_cnt
    u32* hist1     = (u32*)nxt(H1BINS * 4);            //  4096 B
    u32* scal      = (u32*)nxt(64 * 4);                //   256 B
    u64* sel2      = (u64*)nxt((size_t)KSEL * 8);      // 32768 B
    u32* rank      = (u32*)nxt((size_t)CANDCAP * 4);   // 65536 B
    u32* sup_cnt   = (u32*)nxt((size_t)KSEL * 4);      // 16384 B
    u64* cand      = (u64*)nxt((size_t)CANDCAP * 8);
    u64* mask      = (u64*)nxt((size_t)KSEL * 64 * 8);
    u32* sup_ent   = (u32*)nxt((size_t)KSEL * SUPCAP * 4);
    u32* keep_list = (u32*)nxt(512 * 4);
    float4* bb     = (float4*)nxt((size_t)KSEL * 16);
    float* area    = (float*)nxt((size_t)KSEL * 4);
    u32* keys      = (u32*)nxt((size_t)N_ANCH * 4);

    k_zero<<<(ZERO_U4 + 255) / 256, 256, 0, stream>>>((uint4*)hist1);

    k_keys<<<(NQUAD + 1023) / 1024, 1024, 0, stream>>>((const float4*)cls_preds,
                                                       (uint4*)keys, hist1);
    k_scan1<<<1, 1024, 0, stream>>>(hist1, scal);
    k_compact<<<(NQUAD + 255) / 256, 256, 0, stream>>>((const uint4*)keys, scal, cand);
    dim3 rg(CANDCAP / 256, CANDCAP / 512);
    k_rankpart<<<rg, 256, 0, stream>>>(scal, cand, rank);
    k_scatter<<<CANDCAP / 256, 256, 0, stream>>>(scal, cand, rank, sel2);
    k_decode<<<KSEL / 256, 256, 0, stream>>>(sel2, box_preds, anchors, bb, area);
    dim3 mg(64, 64);
    k_mask<<<mg, 64, 0, stream>>>(bb, area, mask, sup_cnt, sup_ent);
    k_serial<<<1, 256, 0, stream>>>(mask, sup_cnt, sup_ent, keep_list, scal);
    k_final<<<2, 256, 0, stream>>>(scal, keep_list, sel2, box_preds, anchors, cls_preds, dir_preds, out);
}